// Round 1
// baseline (1351.083 us; speedup 1.0000x reference)
//
#include <hip/hip_runtime.h>
#include <hip/hip_bf16.h>
#include <math.h>

#define EPSV 1e-5f

// ---------------- degree / norm ----------------
__global__ __launch_bounds__(256) void k_deg(const int* __restrict__ dst,
                                             float* __restrict__ deg, int E) {
  int e = blockIdx.x * 256 + threadIdx.x;
  if (e < E) atomicAdd(&deg[dst[e]], 1.0f);
}

__global__ __launch_bounds__(256) void k_dinv(float* __restrict__ deg, int N) {
  int i = blockIdx.x * 256 + threadIdx.x;
  if (i < N) deg[i] = rsqrtf(deg[i] + 1.0f);  // +1 = self loop
}

// ---------------- GEMM: H[N,DOUT] = X[N,64] @ W[64,DOUT] (+ brow) ----------------
// lane-owns-row: x row in VGPRs, W addresses wave-uniform -> scalar loads (K$),
// no LDS, no bank conflicts. ~80 VGPR.
template <int DOUT>
__global__ __launch_bounds__(256) void k_gemm(const float* __restrict__ X,
                                              const float* __restrict__ W,
                                              const float* __restrict__ brow,
                                              float* __restrict__ H, int N) {
  int row = blockIdx.x * 256 + threadIdx.x;
  if (row >= N) return;
  float4 xv[16];
  const float4* xp = (const float4*)(X + (size_t)row * 64);
#pragma unroll
  for (int i = 0; i < 16; i++) xv[i] = xp[i];
  const float* xs = (const float*)xv;
#pragma unroll 1
  for (int c0 = 0; c0 < DOUT; c0 += 8) {
    float acc[8];
#pragma unroll
    for (int j = 0; j < 8; j++) acc[j] = brow ? brow[c0 + j] : 0.0f;
#pragma unroll
    for (int k = 0; k < 64; k++) {
      float xk = xs[k];
#pragma unroll
      for (int j = 0; j < 8; j++) acc[j] = fmaf(xk, W[k * DOUT + c0 + j], acc[j]);
    }
#pragma unroll
    for (int j = 0; j < 8; j++) H[(size_t)row * DOUT + c0 + j] = acc[j];
  }
}

// ---------------- self-loop init: A = H * dinv^2 (+ bias) ----------------
template <int DOUT>
__global__ __launch_bounds__(256) void k_selfloop(const float* __restrict__ H,
                                                  const float* __restrict__ dinv,
                                                  const float* __restrict__ bias,
                                                  float* __restrict__ A, int N) {
  int i = blockIdx.x * 256 + threadIdx.x;
  if (i >= N * DOUT) return;
  int row = i / DOUT;
  float di = dinv[row];
  float v = H[i] * di * di;
  if (bias) v += bias[i % DOUT];
  A[i] = v;
}

// ---------------- edge scatter: A[dst] += H[src] * dinv[src]*dinv[dst] ----------------
template <int DOUT>
__global__ __launch_bounds__(256) void k_scatter(const float* __restrict__ H,
                                                 const int* __restrict__ src,
                                                 const int* __restrict__ dst,
                                                 const float* __restrict__ dinv,
                                                 float* __restrict__ A, int E) {
  int tid = blockIdx.x * 256 + threadIdx.x;
  int e = tid >> 6, f = tid & 63;
  if (e >= E || f >= DOUT) return;
  int s = src[e], d = dst[e];
  float w = dinv[s] * dinv[d];
  atomicAdd(&A[(size_t)d * DOUT + f], H[(size_t)s * DOUT + f] * w);
}

// ---------------- BN stats: per-feature sum & sumsq over N rows ----------------
__global__ __launch_bounds__(256) void k_bnstats(const float* __restrict__ A,
                                                 float* __restrict__ stats, int N) {
  int f = threadIdx.x & 63;
  int rgrp = threadIdx.x >> 6;  // 0..3
  float s = 0.f, s2 = 0.f;
  for (int r = blockIdx.x * 4 + rgrp; r < N; r += gridDim.x * 4) {
    float v = A[(size_t)r * 64 + f];
    s += v;
    s2 = fmaf(v, v, s2);
  }
  __shared__ float ls[256], ls2[256];
  ls[threadIdx.x] = s;
  ls2[threadIdx.x] = s2;
  __syncthreads();
  if (threadIdx.x < 64) {
    s = ls[f] + ls[f + 64] + ls[f + 128] + ls[f + 192];
    s2 = ls2[f] + ls2[f + 64] + ls2[f + 128] + ls2[f + 192];
    atomicAdd(&stats[f], s);
    atomicAdd(&stats[64 + f], s2);
  }
}

// ---------------- fold BN affine into next-layer weights ----------------
// Wf[k][c] = scale[k]*W[k][c];  brow[c] = sum_k shift[k]*W[k][c]
// scale = g*rsqrt(var+eps), shift = be - mean*scale. (GCN bias b cancels in BN.)
template <int DOUT>
__global__ __launch_bounds__(256) void k_fold(const float* __restrict__ stats,
                                              const float* __restrict__ g,
                                              const float* __restrict__ be,
                                              const float* __restrict__ W,
                                              float* __restrict__ Wf,
                                              float* __restrict__ brow, float invN) {
  __shared__ float scale[64], shift[64];
  int t = threadIdx.x;
  if (t < 64) {
    float mean = stats[t] * invN;
    float var = stats[64 + t] * invN - mean * mean;
    float s = g[t] * rsqrtf(var + EPSV);
    scale[t] = s;
    shift[t] = be[t] - mean * s;
  }
  __syncthreads();
  for (int i = t; i < 64 * DOUT; i += 256) Wf[i] = scale[i / DOUT] * W[i];
  if (t < DOUT) {
    float acc = 0.f;
    for (int k = 0; k < 64; k++) acc = fmaf(shift[k], W[k * DOUT + t], acc);
    brow[t] = acc;
  }
}

// ---------------- log_softmax over 40 cols, one wave per row ----------------
__global__ __launch_bounds__(256) void k_logsoftmax(const float* __restrict__ emb,
                                                    float* __restrict__ out, int N) {
  int wave = (blockIdx.x * 256 + threadIdx.x) >> 6;
  int lane = threadIdx.x & 63;
  if (wave >= N) return;
  float v = (lane < 40) ? emb[(size_t)wave * 40 + lane] : -INFINITY;
  float m = v;
#pragma unroll
  for (int off = 32; off; off >>= 1) m = fmaxf(m, __shfl_xor(m, off));
  float e = (lane < 40) ? expf(v - m) : 0.0f;
  float ssum = e;
#pragma unroll
  for (int off = 32; off; off >>= 1) ssum += __shfl_xor(ssum, off);
  if (lane < 40) out[(size_t)wave * 40 + lane] = v - m - logf(ssum);
}

extern "C" void kernel_launch(void* const* d_in, const int* in_sizes, int n_in,
                              void* d_out, int out_size, void* d_ws, size_t ws_size,
                              hipStream_t stream) {
  const float* x = (const float*)d_in[0];
  const int* ei = (const int*)d_in[1];
  const float* W1 = (const float*)d_in[2];
  // b1 = d_in[3], b2 = d_in[5]: cancel exactly inside BatchNorm (mean subtraction)
  const float* W2 = (const float*)d_in[4];
  const float* W3 = (const float*)d_in[6];
  const float* b3 = (const float*)d_in[7];
  const float* g1 = (const float*)d_in[8];
  const float* be1 = (const float*)d_in[9];
  const float* g2 = (const float*)d_in[10];
  const float* be2 = (const float*)d_in[11];

  int N = in_sizes[0] / 64;
  int E = in_sizes[1] / 2;
  const int* src = ei;
  const int* dst = ei + E;

  size_t nb = (size_t)N * 64 * sizeof(float);
  char* ws = (char*)d_ws;
  float* bufA = (float*)ws;             // [N,64] GEMM outputs (also [N,40] in L3)
  float* bufB = (float*)(ws + nb);      // [N,64] aggregation outputs
  float* dinv = (float*)(ws + 2 * nb);  // [N] deg then rsqrt(deg)
  size_t nvec = (((size_t)N * sizeof(float)) + 255) & ~(size_t)255;
  float* stats = (float*)(ws + 2 * nb + nvec);  // 128
  float* Wf = stats + 128;                      // 64*64 folded weights
  float* brow = Wf + 64 * 64;                   // 64 folded bias row

  float* out = (float*)d_out;
  float* emb = (float*)d_out + (size_t)N * 40;

  dim3 B(256);
  int gN = (N + 255) / 256;
  int gE = (E + 255) / 256;
  int gE64 = (int)(((long long)E * 64 + 255) / 256);
  int gN64 = (int)(((long long)N * 64 + 255) / 256);
  int gN40 = (int)(((long long)N * 40 + 255) / 256);

  // ---- norm ----
  hipMemsetAsync(dinv, 0, (size_t)N * sizeof(float), stream);
  k_deg<<<gE, B, 0, stream>>>(dst, dinv, E);
  k_dinv<<<gN, B, 0, stream>>>(dinv, N);

  // ---- layer 1: h1 = x@W1 ; agg1 = Â h1 ----
  k_gemm<64><<<gN, B, 0, stream>>>(x, W1, nullptr, bufA, N);
  k_selfloop<64><<<gN64, B, 0, stream>>>(bufA, dinv, nullptr, bufB, N);
  k_scatter<64><<<gE64, B, 0, stream>>>(bufA, src, dst, dinv, bufB, E);

  // ---- BN1 folded into W2 ----
  hipMemsetAsync(stats, 0, 128 * sizeof(float), stream);
  k_bnstats<<<256, B, 0, stream>>>(bufB, stats, N);
  k_fold<64><<<1, B, 0, stream>>>(stats, g1, be1, W2, Wf, brow, 1.0f / (float)N);

  // ---- layer 2 ----
  k_gemm<64><<<gN, B, 0, stream>>>(bufB, Wf, brow, bufA, N);
  k_selfloop<64><<<gN64, B, 0, stream>>>(bufA, dinv, nullptr, bufB, N);
  k_scatter<64><<<gE64, B, 0, stream>>>(bufA, src, dst, dinv, bufB, E);

  // ---- BN2 folded into W3 ----
  hipMemsetAsync(stats, 0, 128 * sizeof(float), stream);
  k_bnstats<<<256, B, 0, stream>>>(bufB, stats, N);
  k_fold<40><<<1, B, 0, stream>>>(stats, g2, be2, W3, Wf, brow, 1.0f / (float)N);

  // ---- layer 3: emb = Â (h2n@W3') + b3 ; out = log_softmax(emb) ----
  k_gemm<40><<<gN, B, 0, stream>>>(bufB, Wf, brow, bufA, N);
  k_selfloop<40><<<gN40, B, 0, stream>>>(bufA, dinv, b3, emb, N);
  k_scatter<40><<<gE64, B, 0, stream>>>(bufA, src, dst, dinv, emb, E);
  k_logsoftmax<<<(N + 3) / 4, B, 0, stream>>>(emb, out, N);
}

// Round 2
// 643.230 us; speedup vs baseline: 2.1005x; 2.1005x over previous
//
#include <hip/hip_runtime.h>
#include <hip/hip_bf16.h>
#include <math.h>
#include <stdint.h>

#define EPSV 1e-5f
#define SCAN_CHUNK 2048  // 256 threads x 8 elements

// ---------------- degree (int) ----------------
__global__ __launch_bounds__(256) void k_degi(const int* __restrict__ dst,
                                              int* __restrict__ deg, int E) {
  int e = blockIdx.x * 256 + threadIdx.x;
  if (e < E) atomicAdd(&deg[dst[e]], 1);
}

__global__ __launch_bounds__(256) void k_dinv(const int* __restrict__ deg,
                                              float* __restrict__ dinv, int N) {
  int i = blockIdx.x * 256 + threadIdx.x;
  if (i < N) dinv[i] = rsqrtf((float)deg[i] + 1.0f);  // +1 = self loop
}

// ---------------- exclusive prefix scan of deg -> rowptr ----------------
__global__ __launch_bounds__(256) void k_scan1(const int* __restrict__ deg,
                                               int* __restrict__ rowptr,
                                               int* __restrict__ bsums, int N) {
  __shared__ int lds[256];
  int t = threadIdx.x;
  int base = blockIdx.x * SCAN_CHUNK + t * 8;
  int v[8], s = 0;
#pragma unroll
  for (int j = 0; j < 8; j++) {
    int idx = base + j;
    v[j] = (idx < N) ? deg[idx] : 0;
    s += v[j];
  }
  lds[t] = s;
  __syncthreads();
  for (int off = 1; off < 256; off <<= 1) {
    int tv = (t >= off) ? lds[t - off] : 0;
    __syncthreads();
    if (t >= off) lds[t] += tv;
    __syncthreads();
  }
  if (t == 255) bsums[blockIdx.x] = lds[255];
  int run = (t == 0) ? 0 : lds[t - 1];
#pragma unroll
  for (int j = 0; j < 8; j++) {
    int idx = base + j;
    if (idx < N) rowptr[idx] = run;
    run += v[j];
  }
}

__global__ __launch_bounds__(64) void k_scan2(int* __restrict__ bsums, int nb) {
  int lane = threadIdx.x;
  int v = (lane < nb) ? bsums[lane] : 0;
#pragma unroll
  for (int off = 1; off < 64; off <<= 1) {
    int t = __shfl_up(v, off);
    if (lane >= off) v += t;
  }
  int excl = __shfl_up(v, 1);
  if (lane == 0) excl = 0;
  if (lane < nb) bsums[lane] = excl;
}

__global__ __launch_bounds__(256) void k_scan3(int* __restrict__ rowptr,
                                               const int* __restrict__ bsums,
                                               int* __restrict__ cursor, int N, int E) {
  int i = blockIdx.x * 256 + threadIdx.x;
  if (i < N) {
    int r = rowptr[i] + bsums[i >> 11];
    rowptr[i] = r;
    cursor[i] = r;
  }
  if (i == N) rowptr[N] = E;
}

// ---------------- CSR fill: edges[pos] = {src, dinv[s]*dinv[d]} ----------------
__global__ __launch_bounds__(256) void k_fill(const int* __restrict__ src,
                                              const int* __restrict__ dst,
                                              const float* __restrict__ dinv,
                                              int* __restrict__ cursor,
                                              int2* __restrict__ edges, int E) {
  int e = blockIdx.x * 256 + threadIdx.x;
  if (e >= E) return;
  int s = src[e], d = dst[e];
  int pos = atomicAdd(&cursor[d], 1);
  int2 rec;
  rec.x = s;
  float w = dinv[s] * dinv[d];
  rec.y = __float_as_int(w);
  edges[pos] = rec;
}

// ---------------- GEMM: H[N,DOUT] = X[N,64] @ W[64,DOUT] (+ brow) ----------------
template <int DOUT>
__global__ __launch_bounds__(256) void k_gemm(const float* __restrict__ X,
                                              const float* __restrict__ W,
                                              const float* __restrict__ brow,
                                              float* __restrict__ H, int N) {
  int row = blockIdx.x * 256 + threadIdx.x;
  if (row >= N) return;
  float4 xv[16];
  const float4* xp = (const float4*)(X + (size_t)row * 64);
#pragma unroll
  for (int i = 0; i < 16; i++) xv[i] = xp[i];
  const float* xs = (const float*)xv;
#pragma unroll 1
  for (int c0 = 0; c0 < DOUT; c0 += 8) {
    float acc[8];
#pragma unroll
    for (int j = 0; j < 8; j++) acc[j] = brow ? brow[c0 + j] : 0.0f;
#pragma unroll
    for (int k = 0; k < 64; k++) {
      float xk = xs[k];
#pragma unroll
      for (int j = 0; j < 8; j++) acc[j] = fmaf(xk, W[k * DOUT + c0 + j], acc[j]);
    }
#pragma unroll
    for (int j = 0; j < 8; j++) H[(size_t)row * DOUT + c0 + j] = acc[j];
  }
}

// ---------------- gather aggregation, one wave per dst node ----------------
// A[d] = dinv[d]^2 * H[d] (+bias) + sum_{e in in(d)} w_e * H[src_e]
// Optionally fused log_softmax epilogue (layer 3, DOUT=40).
template <int DOUT, bool LSM>
__global__ __launch_bounds__(256) void k_agg(const float* __restrict__ H,
                                             const int* __restrict__ rowptr,
                                             const int2* __restrict__ edges,
                                             const float* __restrict__ dinv,
                                             const float* __restrict__ bias,
                                             float* __restrict__ A,
                                             float* __restrict__ out, int N) {
  int wid = (blockIdx.x * 256 + threadIdx.x) >> 6;
  int lane = threadIdx.x & 63;
  int node = __builtin_amdgcn_readfirstlane(wid);  // force wave-uniform (SGPR)
  if (node >= N) return;
  int beg = rowptr[node];
  int end = rowptr[node + 1];
  float di = dinv[node];
  float acc0 = (lane < DOUT) ? H[(size_t)node * DOUT + lane] * di * di : 0.0f;
  if (bias && lane < DOUT) acc0 += bias[lane];
  float acc1 = 0.0f;
  int e = beg;
  for (; e + 1 < end; e += 2) {
    int2 r0 = edges[e];
    int2 r1 = edges[e + 1];
    float h0 = H[(size_t)r0.x * DOUT + lane];
    float h1 = H[(size_t)r1.x * DOUT + lane];
    acc0 = fmaf(__int_as_float(r0.y), h0, acc0);
    acc1 = fmaf(__int_as_float(r1.y), h1, acc1);
  }
  if (e < end) {
    int2 r0 = edges[e];
    acc0 = fmaf(__int_as_float(r0.y), H[(size_t)r0.x * DOUT + lane], acc0);
  }
  acc0 += acc1;
  if (!LSM) {
    if (lane < DOUT) A[(size_t)node * DOUT + lane] = acc0;
  } else {
    // A = emb buffer, out = log_softmax output
    float v = (lane < DOUT) ? acc0 : -INFINITY;
    float m = v;
#pragma unroll
    for (int off = 32; off; off >>= 1) m = fmaxf(m, __shfl_xor(m, off));
    float ex = (lane < DOUT) ? expf(v - m) : 0.0f;
    float ssum = ex;
#pragma unroll
    for (int off = 32; off; off >>= 1) ssum += __shfl_xor(ssum, off);
    if (lane < DOUT) {
      A[(size_t)node * DOUT + lane] = acc0;
      out[(size_t)node * DOUT + lane] = acc0 - m - logf(ssum);
    }
  }
}

// ---------------- BN stats: per-feature sum & sumsq ----------------
__global__ __launch_bounds__(256) void k_bnstats(const float* __restrict__ A,
                                                 float* __restrict__ stats, int N) {
  int f = threadIdx.x & 63;
  int rgrp = threadIdx.x >> 6;
  float s = 0.f, s2 = 0.f;
  for (int r = blockIdx.x * 4 + rgrp; r < N; r += gridDim.x * 4) {
    float v = A[(size_t)r * 64 + f];
    s += v;
    s2 = fmaf(v, v, s2);
  }
  __shared__ float ls[256], ls2[256];
  ls[threadIdx.x] = s;
  ls2[threadIdx.x] = s2;
  __syncthreads();
  if (threadIdx.x < 64) {
    s = ls[f] + ls[f + 64] + ls[f + 128] + ls[f + 192];
    s2 = ls2[f] + ls2[f + 64] + ls2[f + 128] + ls2[f + 192];
    atomicAdd(&stats[f], s);
    atomicAdd(&stats[64 + f], s2);
  }
}

// ---------------- fold BN affine into next-layer weights ----------------
template <int DOUT>
__global__ __launch_bounds__(256) void k_fold(const float* __restrict__ stats,
                                              const float* __restrict__ g,
                                              const float* __restrict__ be,
                                              const float* __restrict__ W,
                                              float* __restrict__ Wf,
                                              float* __restrict__ brow, float invN) {
  __shared__ float scale[64], shift[64];
  int t = threadIdx.x;
  if (t < 64) {
    float mean = stats[t] * invN;
    float var = stats[64 + t] * invN - mean * mean;
    float s = g[t] * rsqrtf(var + EPSV);
    scale[t] = s;
    shift[t] = be[t] - mean * s;
  }
  __syncthreads();
  for (int i = t; i < 64 * DOUT; i += 256) Wf[i] = scale[i / DOUT] * W[i];
  if (t < DOUT) {
    float acc = 0.f;
    for (int k = 0; k < 64; k++) acc = fmaf(shift[k], W[k * DOUT + t], acc);
    brow[t] = acc;
  }
}

extern "C" void kernel_launch(void* const* d_in, const int* in_sizes, int n_in,
                              void* d_out, int out_size, void* d_ws, size_t ws_size,
                              hipStream_t stream) {
  const float* x = (const float*)d_in[0];
  const int* ei = (const int*)d_in[1];
  const float* W1 = (const float*)d_in[2];
  // b1 = d_in[3], b2 = d_in[5]: cancel exactly inside BatchNorm (mean subtraction)
  const float* W2 = (const float*)d_in[4];
  const float* W3 = (const float*)d_in[6];
  const float* b3 = (const float*)d_in[7];
  const float* g1 = (const float*)d_in[8];
  const float* be1 = (const float*)d_in[9];
  const float* g2 = (const float*)d_in[10];
  const float* be2 = (const float*)d_in[11];

  int N = in_sizes[0] / 64;
  int E = in_sizes[1] / 2;
  const int* src = ei;
  const int* dst = ei + E;

  char* ws = (char*)d_ws;
  float* bufA = (float*)ws;                      // [N,64]
  float* bufB = bufA + (size_t)N * 64;           // [N,64]
  int* deg = (int*)(bufB + (size_t)N * 64);      // [N]
  float* dinv = (float*)(deg + N);               // [N]
  int* rowptr = (int*)(dinv + N);                // [N+1]
  int* cursor = rowptr + (N + 1);                // [N]
  int* bsums = cursor + N;                       // [64]
  float* stats = (float*)(bsums + 64);           // [128]
  float* Wf = stats + 128;                       // [64*64]
  float* brow = Wf + 64 * 64;                    // [64]
  int2* edges = (int2*)(((uintptr_t)(brow + 64) + 15) & ~(uintptr_t)15);  // [E]

  float* out = (float*)d_out;
  float* emb = (float*)d_out + (size_t)N * 40;

  dim3 B(256);
  int gN = (N + 255) / 256;
  int gE = (E + 255) / 256;
  int nb = (N + SCAN_CHUNK - 1) / SCAN_CHUNK;
  int gW = (N + 3) / 4;  // one wave per node, 4 waves per block

  // ---- CSR build + norm ----
  hipMemsetAsync(deg, 0, (size_t)N * sizeof(int), stream);
  k_degi<<<gE, B, 0, stream>>>(dst, deg, E);
  k_dinv<<<gN, B, 0, stream>>>(deg, dinv, N);
  k_scan1<<<nb, B, 0, stream>>>(deg, rowptr, bsums, N);
  k_scan2<<<1, 64, 0, stream>>>(bsums, nb);
  k_scan3<<<(N + 256) / 256, B, 0, stream>>>(rowptr, bsums, cursor, N, E);
  k_fill<<<gE, B, 0, stream>>>(src, dst, dinv, cursor, edges, E);

  // ---- layer 1 ----
  k_gemm<64><<<gN, B, 0, stream>>>(x, W1, nullptr, bufA, N);
  k_agg<64, false><<<gW, B, 0, stream>>>(bufA, rowptr, edges, dinv, nullptr, bufB, nullptr, N);

  // ---- BN1 folded into W2 ----
  hipMemsetAsync(stats, 0, 128 * sizeof(float), stream);
  k_bnstats<<<256, B, 0, stream>>>(bufB, stats, N);
  k_fold<64><<<1, B, 0, stream>>>(stats, g1, be1, W2, Wf, brow, 1.0f / (float)N);

  // ---- layer 2 ----
  k_gemm<64><<<gN, B, 0, stream>>>(bufB, Wf, brow, bufA, N);
  k_agg<64, false><<<gW, B, 0, stream>>>(bufA, rowptr, edges, dinv, nullptr, bufB, nullptr, N);

  // ---- BN2 folded into W3 ----
  hipMemsetAsync(stats, 0, 128 * sizeof(float), stream);
  k_bnstats<<<256, B, 0, stream>>>(bufB, stats, N);
  k_fold<40><<<1, B, 0, stream>>>(stats, g2, be2, W3, Wf, brow, 1.0f / (float)N);

  // ---- layer 3: gemm -> agg(+b3) -> fused log_softmax ----
  k_gemm<40><<<gN, B, 0, stream>>>(bufB, Wf, brow, bufA, N);
  k_agg<40, true><<<gW, B, 0, stream>>>(bufA, rowptr, edges, dinv, b3, emb, out, N);
}

// Round 3
// 589.279 us; speedup vs baseline: 2.2928x; 1.0916x over previous
//
#include <hip/hip_runtime.h>
#include <hip/hip_bf16.h>
#include <math.h>
#include <stdint.h>

#define EPSV 1e-5f
#define SCAN_CHUNK 2048  // 256 threads x 8 elements

// ---------------- degree (int) ----------------
__global__ __launch_bounds__(256) void k_degi(const int* __restrict__ dst,
                                              int* __restrict__ deg, int E) {
  int e = blockIdx.x * 256 + threadIdx.x;
  if (e < E) atomicAdd(&deg[dst[e]], 1);
}

// ---------------- exclusive prefix scan of deg -> rowptr ----------------
__global__ __launch_bounds__(256) void k_scan1(const int* __restrict__ deg,
                                               int* __restrict__ rowptr,
                                               int* __restrict__ bsums, int N) {
  __shared__ int lds[256];
  int t = threadIdx.x;
  int base = blockIdx.x * SCAN_CHUNK + t * 8;
  int v[8], s = 0;
#pragma unroll
  for (int j = 0; j < 8; j++) {
    int idx = base + j;
    v[j] = (idx < N) ? deg[idx] : 0;
    s += v[j];
  }
  lds[t] = s;
  __syncthreads();
  for (int off = 1; off < 256; off <<= 1) {
    int tv = (t >= off) ? lds[t - off] : 0;
    __syncthreads();
    if (t >= off) lds[t] += tv;
    __syncthreads();
  }
  if (t == 255) bsums[blockIdx.x] = lds[255];
  int run = (t == 0) ? 0 : lds[t - 1];
#pragma unroll
  for (int j = 0; j < 8; j++) {
    int idx = base + j;
    if (idx < N) rowptr[idx] = run;
    run += v[j];
  }
}

__global__ __launch_bounds__(64) void k_scan2(int* __restrict__ bsums, int nb) {
  int lane = threadIdx.x;
  int v = (lane < nb) ? bsums[lane] : 0;
#pragma unroll
  for (int off = 1; off < 64; off <<= 1) {
    int t = __shfl_up(v, off);
    if (lane >= off) v += t;
  }
  int excl = __shfl_up(v, 1);
  if (lane == 0) excl = 0;
  if (lane < nb) bsums[lane] = excl;
}

// scan finalize + cursor init + dinv (folded)
__global__ __launch_bounds__(256) void k_scan3(int* __restrict__ rowptr,
                                               const int* __restrict__ bsums,
                                               const int* __restrict__ deg,
                                               float* __restrict__ dinv,
                                               int* __restrict__ cursor, int N, int E) {
  int i = blockIdx.x * 256 + threadIdx.x;
  if (i < N) {
    int r = rowptr[i] + bsums[i >> 11];
    rowptr[i] = r;
    cursor[i] = r;
    dinv[i] = rsqrtf((float)deg[i] + 1.0f);  // +1 = self loop
  }
  if (i == N) rowptr[N] = E;
}

// ---------------- CSR fill, bucketed by dst range x XCD ----------------
// bucket = blockIdx & 7 ~ XCD id: each XCD writes only its own ~E/8*8B slice of
// edges[], so 64B lines fill up inside one L2 before eviction (kills the 8x
// write amplification seen in R2: WRITE_SIZE 101 MB ~= 64 B/edge).
__global__ __launch_bounds__(256) void k_fill(const int* __restrict__ src,
                                              const int* __restrict__ dst,
                                              const float* __restrict__ dinv,
                                              int* __restrict__ cursor,
                                              int2* __restrict__ edges, int E, int N) {
  int bucket = blockIdx.x & 7;
  int chunk = blockIdx.x >> 3;
  int nch = gridDim.x >> 3;
  int bsz = (N + 7) >> 3;
  int lo = bucket * bsz;
  int hi = min(N, lo + bsz);
  long long per = ((long long)E + nch - 1) / nch;
  int e0 = (int)((long long)chunk * per);
  int e1 = (int)min((long long)E, (long long)e0 + per);
  for (int e = e0 + threadIdx.x; e < e1; e += 256) {
    int d = dst[e];
    if (d < lo || d >= hi) continue;
    int s = src[e];
    int pos = atomicAdd(&cursor[d], 1);
    int2 rec;
    rec.x = s;
    rec.y = __float_as_int(dinv[s] * dinv[d]);
    edges[pos] = rec;
  }
}

// ---------------- GEMM: H[N,DOUT] = X[N,64] @ W[64,DOUT] (+ brow) ----------------
template <int DOUT>
__global__ __launch_bounds__(256) void k_gemm(const float* __restrict__ X,
                                              const float* __restrict__ W,
                                              const float* __restrict__ brow,
                                              float* __restrict__ H, int N) {
  int row = blockIdx.x * 256 + threadIdx.x;
  if (row >= N) return;
  float4 xv[16];
  const float4* xp = (const float4*)(X + (size_t)row * 64);
#pragma unroll
  for (int i = 0; i < 16; i++) xv[i] = xp[i];
  const float* xs = (const float*)xv;
#pragma unroll 1
  for (int c0 = 0; c0 < DOUT; c0 += 8) {
    float acc[8];
#pragma unroll
    for (int j = 0; j < 8; j++) acc[j] = brow ? brow[c0 + j] : 0.0f;
#pragma unroll
    for (int k = 0; k < 64; k++) {
      float xk = xs[k];
#pragma unroll
      for (int j = 0; j < 8; j++) acc[j] = fmaf(xk, W[k * DOUT + c0 + j], acc[j]);
    }
#pragma unroll
    for (int j = 0; j < 8; j++) H[(size_t)row * DOUT + c0 + j] = acc[j];
  }
}

// ---------------- gather aggregation, one wave per dst node ----------------
// Lane-parallel batch load of 64 edge records, then v_readlane broadcast
// (SGPR src -> uniform-base gather), 8-way unrolled, 4 accumulators: MLP per
// wave ~16 outstanding gathers instead of 2 (R2 was latency-bound at 23%
// VALUBusy / 3.25 TB/s).
template <int DOUT, bool LSM>
__global__ __launch_bounds__(256) void k_agg(const float* __restrict__ H,
                                             const int* __restrict__ rowptr,
                                             const int2* __restrict__ edges,
                                             const float* __restrict__ dinv,
                                             const float* __restrict__ bias,
                                             float* __restrict__ A,
                                             float* __restrict__ out, int N) {
  int wid = (blockIdx.x * 256 + threadIdx.x) >> 6;
  int lane = threadIdx.x & 63;
  int node = __builtin_amdgcn_readfirstlane(wid);  // wave-uniform (SGPR)
  if (node >= N) return;
  int beg = rowptr[node];
  int end = rowptr[node + 1];
  float di = dinv[node];
  float acc0 = (lane < DOUT) ? H[(size_t)node * DOUT + lane] * di * di : 0.0f;
  if (bias && lane < DOUT) acc0 += bias[lane];
  float acc1 = 0.f, acc2 = 0.f, acc3 = 0.f;
  for (int b = beg; b < end; b += 64) {
    int cnt = min(64, end - b);
    int2 rec = edges[b + (lane < cnt ? lane : 0)];  // coalesced batch load
    int j = 0;
    for (; j + 8 <= cnt; j += 8) {
      int s0 = __builtin_amdgcn_readlane(rec.x, j + 0);
      int s1 = __builtin_amdgcn_readlane(rec.x, j + 1);
      int s2 = __builtin_amdgcn_readlane(rec.x, j + 2);
      int s3 = __builtin_amdgcn_readlane(rec.x, j + 3);
      int s4 = __builtin_amdgcn_readlane(rec.x, j + 4);
      int s5 = __builtin_amdgcn_readlane(rec.x, j + 5);
      int s6 = __builtin_amdgcn_readlane(rec.x, j + 6);
      int s7 = __builtin_amdgcn_readlane(rec.x, j + 7);
      float w0 = __int_as_float(__builtin_amdgcn_readlane(rec.y, j + 0));
      float w1 = __int_as_float(__builtin_amdgcn_readlane(rec.y, j + 1));
      float w2 = __int_as_float(__builtin_amdgcn_readlane(rec.y, j + 2));
      float w3 = __int_as_float(__builtin_amdgcn_readlane(rec.y, j + 3));
      float w4 = __int_as_float(__builtin_amdgcn_readlane(rec.y, j + 4));
      float w5 = __int_as_float(__builtin_amdgcn_readlane(rec.y, j + 5));
      float w6 = __int_as_float(__builtin_amdgcn_readlane(rec.y, j + 6));
      float w7 = __int_as_float(__builtin_amdgcn_readlane(rec.y, j + 7));
      float h0 = H[(size_t)s0 * DOUT + lane];
      float h1 = H[(size_t)s1 * DOUT + lane];
      float h2 = H[(size_t)s2 * DOUT + lane];
      float h3 = H[(size_t)s3 * DOUT + lane];
      float h4 = H[(size_t)s4 * DOUT + lane];
      float h5 = H[(size_t)s5 * DOUT + lane];
      float h6 = H[(size_t)s6 * DOUT + lane];
      float h7 = H[(size_t)s7 * DOUT + lane];
      acc0 = fmaf(w0, h0, acc0);
      acc1 = fmaf(w1, h1, acc1);
      acc2 = fmaf(w2, h2, acc2);
      acc3 = fmaf(w3, h3, acc3);
      acc0 = fmaf(w4, h4, acc0);
      acc1 = fmaf(w5, h5, acc1);
      acc2 = fmaf(w6, h6, acc2);
      acc3 = fmaf(w7, h7, acc3);
    }
    for (; j < cnt; ++j) {
      int s = __builtin_amdgcn_readlane(rec.x, j);
      float w = __int_as_float(__builtin_amdgcn_readlane(rec.y, j));
      acc0 = fmaf(w, H[(size_t)s * DOUT + lane], acc0);
    }
  }
  acc0 = (acc0 + acc1) + (acc2 + acc3);
  if (!LSM) {
    if (lane < DOUT) A[(size_t)node * DOUT + lane] = acc0;
  } else {
    float v = (lane < DOUT) ? acc0 : -INFINITY;
    float m = v;
#pragma unroll
    for (int off = 32; off; off >>= 1) m = fmaxf(m, __shfl_xor(m, off));
    float ex = (lane < DOUT) ? expf(v - m) : 0.0f;
    float ssum = ex;
#pragma unroll
    for (int off = 32; off; off >>= 1) ssum += __shfl_xor(ssum, off);
    if (lane < DOUT) {
      A[(size_t)node * DOUT + lane] = acc0;
      out[(size_t)node * DOUT + lane] = acc0 - m - logf(ssum);
    }
  }
}

// ---------------- BN stats: per-block partials (no atomics, no memset) ----------------
__global__ __launch_bounds__(256) void k_bnstats(const float* __restrict__ A,
                                                 float* __restrict__ stats, int N) {
  int f = threadIdx.x & 63;
  int rgrp = threadIdx.x >> 6;
  float s = 0.f, s2 = 0.f;
  for (int r = blockIdx.x * 4 + rgrp; r < N; r += gridDim.x * 4) {
    float v = A[(size_t)r * 64 + f];
    s += v;
    s2 = fmaf(v, v, s2);
  }
  __shared__ float ls[256], ls2[256];
  ls[threadIdx.x] = s;
  ls2[threadIdx.x] = s2;
  __syncthreads();
  if (threadIdx.x < 64) {
    s = ls[f] + ls[f + 64] + ls[f + 128] + ls[f + 192];
    s2 = ls2[f] + ls2[f + 64] + ls2[f + 128] + ls2[f + 192];
    stats[(size_t)blockIdx.x * 128 + f] = s;
    stats[(size_t)blockIdx.x * 128 + 64 + f] = s2;
  }
}

// ---------------- reduce partials + fold BN affine into next-layer weights ----------------
template <int DOUT>
__global__ __launch_bounds__(256) void k_fold(const float* __restrict__ stats,
                                              const float* __restrict__ g,
                                              const float* __restrict__ be,
                                              const float* __restrict__ W,
                                              float* __restrict__ Wf,
                                              float* __restrict__ brow, float invN) {
  __shared__ float red[128];
  __shared__ float scale[64], shift[64];
  int t = threadIdx.x;
  if (t < 128) {
    float sacc = 0.f;
    for (int b = 0; b < 256; b++) sacc += stats[(size_t)b * 128 + t];
    red[t] = sacc;
  }
  __syncthreads();
  if (t < 64) {
    float mean = red[t] * invN;
    float var = red[64 + t] * invN - mean * mean;
    float sc = g[t] * rsqrtf(var + EPSV);
    scale[t] = sc;
    shift[t] = be[t] - mean * sc;
  }
  __syncthreads();
  for (int i = t; i < 64 * DOUT; i += 256) Wf[i] = scale[i / DOUT] * W[i];
  if (t < DOUT) {
    float acc = 0.f;
    for (int k = 0; k < 64; k++) acc = fmaf(shift[k], W[k * DOUT + t], acc);
    brow[t] = acc;
  }
}

extern "C" void kernel_launch(void* const* d_in, const int* in_sizes, int n_in,
                              void* d_out, int out_size, void* d_ws, size_t ws_size,
                              hipStream_t stream) {
  const float* x = (const float*)d_in[0];
  const int* ei = (const int*)d_in[1];
  const float* W1 = (const float*)d_in[2];
  // b1 = d_in[3], b2 = d_in[5]: cancel exactly inside BatchNorm (mean subtraction)
  const float* W2 = (const float*)d_in[4];
  const float* W3 = (const float*)d_in[6];
  const float* b3 = (const float*)d_in[7];
  const float* g1 = (const float*)d_in[8];
  const float* be1 = (const float*)d_in[9];
  const float* g2 = (const float*)d_in[10];
  const float* be2 = (const float*)d_in[11];

  int N = in_sizes[0] / 64;
  int E = in_sizes[1] / 2;
  const int* src = ei;
  const int* dst = ei + E;

  char* ws = (char*)d_ws;
  float* bufA = (float*)ws;                      // [N,64]
  float* bufB = bufA + (size_t)N * 64;           // [N,64]
  int* deg = (int*)(bufB + (size_t)N * 64);      // [N]
  float* dinv = (float*)(deg + N);               // [N]
  int* rowptr = (int*)(dinv + N);                // [N+1]
  int* cursor = rowptr + (N + 1);                // [N]
  int* bsums = cursor + N;                       // [64]
  float* stats = (float*)(bsums + 64);           // [256*128] partials
  float* Wf = stats + 256 * 128;                 // [64*64]
  float* brow = Wf + 64 * 64;                    // [64]
  int2* edges = (int2*)(((uintptr_t)(brow + 64) + 15) & ~(uintptr_t)15);  // [E]

  float* out = (float*)d_out;
  float* emb = (float*)d_out + (size_t)N * 40;

  dim3 B(256);
  int gN = (N + 255) / 256;
  int gE = (E + 255) / 256;
  int nb = (N + SCAN_CHUNK - 1) / SCAN_CHUNK;
  int gW = (N + 3) / 4;  // one wave per node, 4 waves per block

  // ---- CSR build + norm ----
  hipMemsetAsync(deg, 0, (size_t)N * sizeof(int), stream);
  k_degi<<<gE, B, 0, stream>>>(dst, deg, E);
  k_scan1<<<nb, B, 0, stream>>>(deg, rowptr, bsums, N);
  k_scan2<<<1, 64, 0, stream>>>(bsums, nb);
  k_scan3<<<(N + 256) / 256, B, 0, stream>>>(rowptr, bsums, deg, dinv, cursor, N, E);
  k_fill<<<8 * 96, B, 0, stream>>>(src, dst, dinv, cursor, edges, E, N);

  // ---- layer 1 ----
  k_gemm<64><<<gN, B, 0, stream>>>(x, W1, nullptr, bufA, N);
  k_agg<64, false><<<gW, B, 0, stream>>>(bufA, rowptr, edges, dinv, nullptr, bufB, nullptr, N);

  // ---- BN1 folded into W2 ----
  k_bnstats<<<256, B, 0, stream>>>(bufB, stats, N);
  k_fold<64><<<1, B, 0, stream>>>(stats, g1, be1, W2, Wf, brow, 1.0f / (float)N);

  // ---- layer 2 ----
  k_gemm<64><<<gN, B, 0, stream>>>(bufB, Wf, brow, bufA, N);
  k_agg<64, false><<<gW, B, 0, stream>>>(bufA, rowptr, edges, dinv, nullptr, bufB, nullptr, N);

  // ---- BN2 folded into W3 ----
  k_bnstats<<<256, B, 0, stream>>>(bufB, stats, N);
  k_fold<40><<<1, B, 0, stream>>>(stats, g2, be2, W3, Wf, brow, 1.0f / (float)N);

  // ---- layer 3: gemm -> agg(+b3) -> fused log_softmax ----
  k_gemm<40><<<gN, B, 0, stream>>>(bufB, Wf, brow, bufA, N);
  k_agg<40, true><<<gW, B, 0, stream>>>(bufA, rowptr, edges, dinv, b3, emb, out, N);
}

// Round 4
// 559.053 us; speedup vs baseline: 2.4167x; 1.0541x over previous
//
#include <hip/hip_runtime.h>
#include <hip/hip_bf16.h>
#include <math.h>
#include <stdint.h>

#define EPSV 1e-5f
#define SCAN_CHUNK 2048  // 256 threads x 8 elements
#define BCAP 2560        // bucket capacity: mean 2048, sigma ~45 -> 11 sigma slack
#define NBMAX 1024       // >= ceil(N/128)

// ---------------- degree (int) ----------------
__global__ __launch_bounds__(256) void k_degi(const int* __restrict__ dst,
                                              int* __restrict__ deg, int E) {
  int e = blockIdx.x * 256 + threadIdx.x;
  if (e < E) atomicAdd(&deg[dst[e]], 1);
}

// ---------------- exclusive prefix scan of deg -> rowptr ----------------
__global__ __launch_bounds__(256) void k_scan1(const int* __restrict__ deg,
                                               int* __restrict__ rowptr,
                                               int* __restrict__ bsums, int N) {
  __shared__ int lds[256];
  int t = threadIdx.x;
  int base = blockIdx.x * SCAN_CHUNK + t * 8;
  int v[8], s = 0;
#pragma unroll
  for (int j = 0; j < 8; j++) {
    int idx = base + j;
    v[j] = (idx < N) ? deg[idx] : 0;
    s += v[j];
  }
  lds[t] = s;
  __syncthreads();
  for (int off = 1; off < 256; off <<= 1) {
    int tv = (t >= off) ? lds[t - off] : 0;
    __syncthreads();
    if (t >= off) lds[t] += tv;
    __syncthreads();
  }
  if (t == 255) bsums[blockIdx.x] = lds[255];
  int run = (t == 0) ? 0 : lds[t - 1];
#pragma unroll
  for (int j = 0; j < 8; j++) {
    int idx = base + j;
    if (idx < N) rowptr[idx] = run;
    run += v[j];
  }
}

__global__ __launch_bounds__(64) void k_scan2(int* __restrict__ bsums, int nb) {
  int lane = threadIdx.x;
  int v = (lane < nb) ? bsums[lane] : 0;
#pragma unroll
  for (int off = 1; off < 64; off <<= 1) {
    int t = __shfl_up(v, off);
    if (lane >= off) v += t;
  }
  int excl = __shfl_up(v, 1);
  if (lane == 0) excl = 0;
  if (lane < nb) bsums[lane] = excl;
}

// scan finalize + dinv (folded)
__global__ __launch_bounds__(256) void k_scan3(int* __restrict__ rowptr,
                                               const int* __restrict__ bsums,
                                               const int* __restrict__ deg,
                                               float* __restrict__ dinv, int N, int E) {
  int i = blockIdx.x * 256 + threadIdx.x;
  if (i < N) {
    rowptr[i] = rowptr[i] + bsums[i >> 11];
    dinv[i] = rsqrtf((float)deg[i] + 1.0f);  // +1 = self loop
  }
  if (i == N) rowptr[N] = E;
}

// ---------------- phase A: bin edges into 128-node buckets ----------------
// Active write-tail set = NB (~782) lines ~ 50 KB << per-XCD L2, so 64B lines
// fill before eviction (R2/R3 scatter had 100K tail lines = 6.4MB -> 8x write
// amplification). Records are 4B packed: src | d_local<<20.
__global__ __launch_bounds__(256) void k_binA(const int* __restrict__ src,
                                              const int* __restrict__ dst,
                                              int* __restrict__ gcount,
                                              int* __restrict__ staging, int E, int NB) {
  __shared__ int hist[NBMAX];
  __shared__ int gbase[NBMAX];
  int t = threadIdx.x;
  for (int b = t; b < NB; b += 256) hist[b] = 0;
  __syncthreads();
  int e0 = blockIdx.x * 4096;
  int sreg[16], dreg[16];
#pragma unroll
  for (int j = 0; j < 16; j++) {
    int e = e0 + j * 256 + t;
    if (e < E) {
      sreg[j] = src[e];
      dreg[j] = dst[e];
      atomicAdd(&hist[dreg[j] >> 7], 1);
    } else {
      dreg[j] = -1;
    }
  }
  __syncthreads();
  for (int b = t; b < NB; b += 256) {
    int c = hist[b];
    if (c) gbase[b] = b * BCAP + atomicAdd(&gcount[b], c);
    hist[b] = 0;  // reuse as local rank counter
  }
  __syncthreads();
#pragma unroll
  for (int j = 0; j < 16; j++) {
    if (dreg[j] >= 0) {
      int b = dreg[j] >> 7;
      int r = atomicAdd(&hist[b], 1);
      int pos = gbase[b] + r;
      if (pos < (b + 1) * BCAP)  // overflow guard (statistically impossible)
        staging[pos] = sreg[j] | ((dreg[j] & 127) << 20);
    }
  }
}

// ---------------- phase B: bucket -> exact per-node CSR ----------------
// One block per bucket; output window (~16KB contiguous) written within one
// block's timeslice -> L2-hot, write amplification ~1.
__global__ __launch_bounds__(256) void k_binB(const int* __restrict__ staging,
                                              const int* __restrict__ gcount,
                                              const int* __restrict__ rowptr,
                                              const float* __restrict__ dinv,
                                              int2* __restrict__ edges, int N) {
  __shared__ int cur[128];
  __shared__ float din[128];
  int b = blockIdx.x;
  int t = threadIdx.x;
  int lo = b * 128;
  int nn = min(128, N - lo);
  if (t < nn) {
    cur[t] = rowptr[lo + t];
    din[t] = dinv[lo + t];
  }
  __syncthreads();
  int cnt = gcount[b];
  for (int r = t; r < cnt; r += 256) {
    int rec = staging[b * BCAP + r];
    int s = rec & 0xFFFFF;
    int dl = rec >> 20;
    int pos = atomicAdd(&cur[dl], 1);
    int2 out;
    out.x = s;
    out.y = __float_as_int(dinv[s] * din[dl]);
    edges[pos] = out;
  }
}

// ---------------- GEMM: H[N,DOUT] = X[N,64] @ W[64,DOUT] (+ brow) ----------------
template <int DOUT>
__global__ __launch_bounds__(256) void k_gemm(const float* __restrict__ X,
                                              const float* __restrict__ W,
                                              const float* __restrict__ brow,
                                              float* __restrict__ H, int N) {
  int row = blockIdx.x * 256 + threadIdx.x;
  if (row >= N) return;
  float4 xv[16];
  const float4* xp = (const float4*)(X + (size_t)row * 64);
#pragma unroll
  for (int i = 0; i < 16; i++) xv[i] = xp[i];
  const float* xs = (const float*)xv;
#pragma unroll 1
  for (int c0 = 0; c0 < DOUT; c0 += 8) {
    float acc[8];
#pragma unroll
    for (int j = 0; j < 8; j++) acc[j] = brow ? brow[c0 + j] : 0.0f;
#pragma unroll
    for (int k = 0; k < 64; k++) {
      float xk = xs[k];
#pragma unroll
      for (int j = 0; j < 8; j++) acc[j] = fmaf(xk, W[k * DOUT + c0 + j], acc[j]);
    }
#pragma unroll
    for (int j = 0; j < 8; j++) H[(size_t)row * DOUT + c0 + j] = acc[j];
  }
}

// ---------------- gather aggregation, one wave per dst node ----------------
template <int DOUT, bool LSM>
__global__ __launch_bounds__(256) void k_agg(const float* __restrict__ H,
                                             const int* __restrict__ rowptr,
                                             const int2* __restrict__ edges,
                                             const float* __restrict__ dinv,
                                             const float* __restrict__ bias,
                                             float* __restrict__ A,
                                             float* __restrict__ out, int N) {
  int wid = (blockIdx.x * 256 + threadIdx.x) >> 6;
  int lane = threadIdx.x & 63;
  int node = __builtin_amdgcn_readfirstlane(wid);  // wave-uniform (SGPR)
  if (node >= N) return;
  int beg = rowptr[node];
  int end = rowptr[node + 1];
  float di = dinv[node];
  float acc0 = (lane < DOUT) ? H[(size_t)node * DOUT + lane] * di * di : 0.0f;
  if (bias && lane < DOUT) acc0 += bias[lane];
  float acc1 = 0.f, acc2 = 0.f, acc3 = 0.f;
  for (int b = beg; b < end; b += 64) {
    int cnt = min(64, end - b);
    int2 rec = edges[b + (lane < cnt ? lane : 0)];  // coalesced batch load
    int j = 0;
    for (; j + 8 <= cnt; j += 8) {
      int s0 = __builtin_amdgcn_readlane(rec.x, j + 0);
      int s1 = __builtin_amdgcn_readlane(rec.x, j + 1);
      int s2 = __builtin_amdgcn_readlane(rec.x, j + 2);
      int s3 = __builtin_amdgcn_readlane(rec.x, j + 3);
      int s4 = __builtin_amdgcn_readlane(rec.x, j + 4);
      int s5 = __builtin_amdgcn_readlane(rec.x, j + 5);
      int s6 = __builtin_amdgcn_readlane(rec.x, j + 6);
      int s7 = __builtin_amdgcn_readlane(rec.x, j + 7);
      float w0 = __int_as_float(__builtin_amdgcn_readlane(rec.y, j + 0));
      float w1 = __int_as_float(__builtin_amdgcn_readlane(rec.y, j + 1));
      float w2 = __int_as_float(__builtin_amdgcn_readlane(rec.y, j + 2));
      float w3 = __int_as_float(__builtin_amdgcn_readlane(rec.y, j + 3));
      float w4 = __int_as_float(__builtin_amdgcn_readlane(rec.y, j + 4));
      float w5 = __int_as_float(__builtin_amdgcn_readlane(rec.y, j + 5));
      float w6 = __int_as_float(__builtin_amdgcn_readlane(rec.y, j + 6));
      float w7 = __int_as_float(__builtin_amdgcn_readlane(rec.y, j + 7));
      float h0 = H[(size_t)s0 * DOUT + lane];
      float h1 = H[(size_t)s1 * DOUT + lane];
      float h2 = H[(size_t)s2 * DOUT + lane];
      float h3 = H[(size_t)s3 * DOUT + lane];
      float h4 = H[(size_t)s4 * DOUT + lane];
      float h5 = H[(size_t)s5 * DOUT + lane];
      float h6 = H[(size_t)s6 * DOUT + lane];
      float h7 = H[(size_t)s7 * DOUT + lane];
      acc0 = fmaf(w0, h0, acc0);
      acc1 = fmaf(w1, h1, acc1);
      acc2 = fmaf(w2, h2, acc2);
      acc3 = fmaf(w3, h3, acc3);
      acc0 = fmaf(w4, h4, acc0);
      acc1 = fmaf(w5, h5, acc1);
      acc2 = fmaf(w6, h6, acc2);
      acc3 = fmaf(w7, h7, acc3);
    }
    for (; j < cnt; ++j) {
      int s = __builtin_amdgcn_readlane(rec.x, j);
      float w = __int_as_float(__builtin_amdgcn_readlane(rec.y, j));
      acc0 = fmaf(w, H[(size_t)s * DOUT + lane], acc0);
    }
  }
  acc0 = (acc0 + acc1) + (acc2 + acc3);
  if (!LSM) {
    if (lane < DOUT) A[(size_t)node * DOUT + lane] = acc0;
  } else {
    float v = (lane < DOUT) ? acc0 : -INFINITY;
    float m = v;
#pragma unroll
    for (int off = 32; off; off >>= 1) m = fmaxf(m, __shfl_xor(m, off));
    float ex = (lane < DOUT) ? expf(v - m) : 0.0f;
    float ssum = ex;
#pragma unroll
    for (int off = 32; off; off >>= 1) ssum += __shfl_xor(ssum, off);
    if (lane < DOUT) {
      A[(size_t)node * DOUT + lane] = acc0;
      out[(size_t)node * DOUT + lane] = acc0 - m - logf(ssum);
    }
  }
}

// ---------------- BN stats: per-block partials (no atomics, no memset) ----------------
__global__ __launch_bounds__(256) void k_bnstats(const float* __restrict__ A,
                                                 float* __restrict__ stats, int N) {
  int f = threadIdx.x & 63;
  int rgrp = threadIdx.x >> 6;
  float s = 0.f, s2 = 0.f;
  for (int r = blockIdx.x * 4 + rgrp; r < N; r += gridDim.x * 4) {
    float v = A[(size_t)r * 64 + f];
    s += v;
    s2 = fmaf(v, v, s2);
  }
  __shared__ float ls[256], ls2[256];
  ls[threadIdx.x] = s;
  ls2[threadIdx.x] = s2;
  __syncthreads();
  if (threadIdx.x < 64) {
    s = ls[f] + ls[f + 64] + ls[f + 128] + ls[f + 192];
    s2 = ls2[f] + ls2[f + 64] + ls2[f + 128] + ls2[f + 192];
    stats[(size_t)blockIdx.x * 128 + f] = s;
    stats[(size_t)blockIdx.x * 128 + 64 + f] = s2;
  }
}

// ---------------- reduce partials + fold BN affine into next-layer weights ----------------
template <int DOUT>
__global__ __launch_bounds__(256) void k_fold(const float* __restrict__ stats,
                                              const float* __restrict__ g,
                                              const float* __restrict__ be,
                                              const float* __restrict__ W,
                                              float* __restrict__ Wf,
                                              float* __restrict__ brow, float invN) {
  __shared__ float red[128];
  __shared__ float scale[64], shift[64];
  int t = threadIdx.x;
  if (t < 128) {
    float sacc = 0.f;
    for (int b = 0; b < 256; b++) sacc += stats[(size_t)b * 128 + t];
    red[t] = sacc;
  }
  __syncthreads();
  if (t < 64) {
    float mean = red[t] * invN;
    float var = red[64 + t] * invN - mean * mean;
    float sc = g[t] * rsqrtf(var + EPSV);
    scale[t] = sc;
    shift[t] = be[t] - mean * sc;
  }
  __syncthreads();
  for (int i = t; i < 64 * DOUT; i += 256) Wf[i] = scale[i / DOUT] * W[i];
  if (t < DOUT) {
    float acc = 0.f;
    for (int k = 0; k < 64; k++) acc = fmaf(shift[k], W[k * DOUT + t], acc);
    brow[t] = acc;
  }
}

extern "C" void kernel_launch(void* const* d_in, const int* in_sizes, int n_in,
                              void* d_out, int out_size, void* d_ws, size_t ws_size,
                              hipStream_t stream) {
  const float* x = (const float*)d_in[0];
  const int* ei = (const int*)d_in[1];
  const float* W1 = (const float*)d_in[2];
  // b1 = d_in[3], b2 = d_in[5]: cancel exactly inside BatchNorm (mean subtraction)
  const float* W2 = (const float*)d_in[4];
  const float* W3 = (const float*)d_in[6];
  const float* b3 = (const float*)d_in[7];
  const float* g1 = (const float*)d_in[8];
  const float* be1 = (const float*)d_in[9];
  const float* g2 = (const float*)d_in[10];
  const float* be2 = (const float*)d_in[11];

  int N = in_sizes[0] / 64;
  int E = in_sizes[1] / 2;
  const int* src = ei;
  const int* dst = ei + E;
  int NB = (N + 127) / 128;  // 128-node buckets

  char* ws = (char*)d_ws;
  float* bufA = (float*)ws;                      // [N,64]; staging aliased here
  float* bufB = bufA + (size_t)N * 64;           // [N,64]
  int* deg = (int*)(bufB + (size_t)N * 64);      // [N]
  int* gcount = deg + N;                         // [NBMAX] (memset with deg)
  float* dinv = (float*)(gcount + NBMAX);        // [N]
  int* rowptr = (int*)(dinv + N);                // [N+1]
  int* bsums = rowptr + (N + 1);                 // [64]
  float* stats = (float*)(bsums + 64);           // [256*128] partials
  float* Wf = stats + 256 * 128;                 // [64*64]
  float* brow = Wf + 64 * 64;                    // [64]
  int2* edges = (int2*)(((uintptr_t)(brow + 64) + 15) & ~(uintptr_t)15);  // [E]
  int* staging = (int*)bufA;                     // [NB*BCAP] 4B recs (pre-gemm only)

  float* out = (float*)d_out;
  float* emb = (float*)d_out + (size_t)N * 40;

  dim3 B(256);
  int gN = (N + 255) / 256;
  int gE = (E + 255) / 256;
  int nb = (N + SCAN_CHUNK - 1) / SCAN_CHUNK;
  int gW = (N + 3) / 4;  // one wave per node, 4 waves per block

  // ---- CSR build + norm ----
  hipMemsetAsync(deg, 0, ((size_t)N + NBMAX) * sizeof(int), stream);
  k_degi<<<gE, B, 0, stream>>>(dst, deg, E);
  k_scan1<<<nb, B, 0, stream>>>(deg, rowptr, bsums, N);
  k_scan2<<<1, 64, 0, stream>>>(bsums, nb);
  k_scan3<<<(N + 256) / 256, B, 0, stream>>>(rowptr, bsums, deg, dinv, N, E);
  k_binA<<<(E + 4095) / 4096, B, 0, stream>>>(src, dst, gcount, staging, E, NB);
  k_binB<<<NB, B, 0, stream>>>(staging, gcount, rowptr, dinv, edges, N);

  // ---- layer 1 ----
  k_gemm<64><<<gN, B, 0, stream>>>(x, W1, nullptr, bufA, N);
  k_agg<64, false><<<gW, B, 0, stream>>>(bufA, rowptr, edges, dinv, nullptr, bufB, nullptr, N);

  // ---- BN1 folded into W2 ----
  k_bnstats<<<256, B, 0, stream>>>(bufB, stats, N);
  k_fold<64><<<1, B, 0, stream>>>(stats, g1, be1, W2, Wf, brow, 1.0f / (float)N);

  // ---- layer 2 ----
  k_gemm<64><<<gN, B, 0, stream>>>(bufB, Wf, brow, bufA, N);
  k_agg<64, false><<<gW, B, 0, stream>>>(bufA, rowptr, edges, dinv, nullptr, bufB, nullptr, N);

  // ---- BN2 folded into W3 ----
  k_bnstats<<<256, B, 0, stream>>>(bufB, stats, N);
  k_fold<40><<<1, B, 0, stream>>>(stats, g2, be2, W3, Wf, brow, 1.0f / (float)N);

  // ---- layer 3: gemm -> agg(+b3) -> fused log_softmax ----
  k_gemm<40><<<gN, B, 0, stream>>>(bufB, Wf, brow, bufA, N);
  k_agg<40, true><<<gW, B, 0, stream>>>(bufA, rowptr, edges, dinv, b3, emb, out, N);
}

// Round 5
// 408.068 us; speedup vs baseline: 3.3109x; 1.3700x over previous
//
#include <hip/hip_runtime.h>
#include <hip/hip_bf16.h>
#include <math.h>
#include <stdint.h>

#define EPSV 1e-5f
#define BCAP 2560        // bucket capacity: mean 2048, sigma ~45 -> 11 sigma slack
#define NBMAX 1024       // >= ceil(N/128)
#define SLOTS 128        // BN-stat partial slots

static __device__ __forceinline__ float bf_lo(unsigned int u) {
  union { unsigned int i; float f; } v; v.i = u << 16; return v.f;
}
static __device__ __forceinline__ float bf_hi(unsigned int u) {
  union { unsigned int i; float f; } v; v.i = u & 0xffff0000u; return v.f;
}
static __device__ __forceinline__ float bf2f(unsigned short u) {
  union { unsigned int i; float f; } v; v.i = ((unsigned int)u) << 16; return v.f;
}
static __device__ __forceinline__ unsigned short f2bf(float f) {
  union { float f; unsigned int i; } v; v.f = f;
  unsigned int r = v.i + 0x7fff + ((v.i >> 16) & 1);  // RTNE
  return (unsigned short)(r >> 16);
}

// ---------------- phase A: bin edges into 128-node buckets ----------------
// Active write-tail set = NB (~782) lines ~ 50 KB << per-XCD L2 -> lines fill
// before eviction (write amplification ~1). Record: src | d_local<<20.
__global__ __launch_bounds__(256) void k_binA(const int* __restrict__ src,
                                              const int* __restrict__ dst,
                                              int* __restrict__ gcount,
                                              int* __restrict__ staging, int E, int NB) {
  __shared__ int hist[NBMAX];
  __shared__ int gbase[NBMAX];
  int t = threadIdx.x;
  for (int b = t; b < NB; b += 256) hist[b] = 0;
  __syncthreads();
  int e0 = blockIdx.x * 4096;
  int sreg[16], dreg[16];
#pragma unroll
  for (int j = 0; j < 16; j++) {
    int e = e0 + j * 256 + t;
    if (e < E) {
      sreg[j] = src[e];
      dreg[j] = dst[e];
      atomicAdd(&hist[dreg[j] >> 7], 1);
    } else {
      dreg[j] = -1;
    }
  }
  __syncthreads();
  for (int b = t; b < NB; b += 256) {
    int c = hist[b];
    if (c) gbase[b] = b * BCAP + atomicAdd(&gcount[b], c);
    hist[b] = 0;  // reuse as local rank counter
  }
  __syncthreads();
#pragma unroll
  for (int j = 0; j < 16; j++) {
    if (dreg[j] >= 0) {
      int b = dreg[j] >> 7;
      int r = atomicAdd(&hist[b], 1);
      int pos = gbase[b] + r;
      if (pos < (b + 1) * BCAP)  // overflow guard (statistically impossible)
        staging[pos] = sreg[j] | ((dreg[j] & 127) << 20);
    }
  }
}

// ---------------- exclusive scan of gcount -> bucket bases ----------------
__global__ __launch_bounds__(256) void k_scanb(const int* __restrict__ gcount,
                                               int* __restrict__ bbase,
                                               int* __restrict__ rowptr, int NB, int N,
                                               int E) {
  __shared__ int lds[256];
  int t = threadIdx.x;
  int v[4], s = 0;
#pragma unroll
  for (int j = 0; j < 4; j++) {
    int idx = t * 4 + j;
    v[j] = (idx < NB) ? gcount[idx] : 0;
    s += v[j];
  }
  lds[t] = s;
  __syncthreads();
  for (int off = 1; off < 256; off <<= 1) {
    int tv = (t >= off) ? lds[t - off] : 0;
    __syncthreads();
    if (t >= off) lds[t] += tv;
    __syncthreads();
  }
  int run = (t == 0) ? 0 : lds[t - 1];
#pragma unroll
  for (int j = 0; j < 4; j++) {
    int idx = t * 4 + j;
    if (idx < NB) bbase[idx] = run;
    run += v[j];
  }
  if (t == 0) rowptr[N] = E;
}

// ---------------- phase B: bucket -> exact CSR + rowptr + dinv ----------------
// Staging records cached in LDS (single global read); per-node counts give
// degree -> dinv and rowptr (no separate degi/scan-over-N kernels needed).
__global__ __launch_bounds__(256) void k_binB(const int* __restrict__ staging,
                                              const int* __restrict__ gcount,
                                              const int* __restrict__ bbase,
                                              int* __restrict__ rowptr,
                                              float* __restrict__ dinv,
                                              int* __restrict__ edges, int N) {
  __shared__ int rec[BCAP];
  __shared__ int cnt[128], cur[128], scn[128];
  int b = blockIdx.x;
  int t = threadIdx.x;
  int lo = b * 128;
  int nn = min(128, N - lo);
  int c = min(gcount[b], BCAP);
  if (t < 128) cnt[t] = 0;
  __syncthreads();
  for (int r = t; r < c; r += 256) {
    int x = staging[b * BCAP + r];
    rec[r] = x;
    atomicAdd(&cnt[x >> 20], 1);
  }
  __syncthreads();
  if (t < 128) scn[t] = cnt[t];
  __syncthreads();
  for (int off = 1; off < 128; off <<= 1) {
    int tv = (t < 128 && t >= off) ? scn[t - off] : 0;
    __syncthreads();
    if (t < 128 && t >= off) scn[t] += tv;
    __syncthreads();
  }
  int base = bbase[b];
  if (t < 128) {
    int excl = (t == 0) ? 0 : scn[t - 1];
    cur[t] = excl;
    if (t < nn) {
      rowptr[lo + t] = base + excl;
      dinv[lo + t] = rsqrtf((float)cnt[t] + 1.0f);  // +1 = self loop
    }
  }
  __syncthreads();
  for (int r = t; r < c; r += 256) {
    int x = rec[r];
    int pos = base + atomicAdd(&cur[x >> 20], 1);
    edges[pos] = x & 0xFFFFF;
  }
}

// ---------------- GEMM: Hs[r] = dinv[r] * (X[r] @ W + brow), bf16 out ----------------
template <int DOUT, bool BFIN>
__global__ __launch_bounds__(256) void k_gemm(const void* __restrict__ Xv,
                                              const float* __restrict__ W,
                                              const float* __restrict__ brow,
                                              const float* __restrict__ dinv,
                                              unsigned short* __restrict__ Hs, int N) {
  int row = blockIdx.x * 256 + threadIdx.x;
  if (row >= N) return;
  float xs[64];
  if (BFIN) {
    const uint4* xp = (const uint4*)((const unsigned short*)Xv + (size_t)row * 64);
#pragma unroll
    for (int i = 0; i < 8; i++) {
      uint4 u = xp[i];
      xs[i * 8 + 0] = bf_lo(u.x); xs[i * 8 + 1] = bf_hi(u.x);
      xs[i * 8 + 2] = bf_lo(u.y); xs[i * 8 + 3] = bf_hi(u.y);
      xs[i * 8 + 4] = bf_lo(u.z); xs[i * 8 + 5] = bf_hi(u.z);
      xs[i * 8 + 6] = bf_lo(u.w); xs[i * 8 + 7] = bf_hi(u.w);
    }
  } else {
    const float4* xp = (const float4*)((const float*)Xv + (size_t)row * 64);
#pragma unroll
    for (int i = 0; i < 16; i++) {
      float4 f = xp[i];
      xs[i * 4 + 0] = f.x; xs[i * 4 + 1] = f.y;
      xs[i * 4 + 2] = f.z; xs[i * 4 + 3] = f.w;
    }
  }
  float di = dinv[row];
#pragma unroll 1
  for (int c0 = 0; c0 < DOUT; c0 += 8) {
    float acc[8];
#pragma unroll
    for (int j = 0; j < 8; j++) acc[j] = brow ? brow[c0 + j] : 0.0f;
#pragma unroll
    for (int k = 0; k < 64; k++) {
      float xk = xs[k];
#pragma unroll
      for (int j = 0; j < 8; j++) acc[j] = fmaf(xk, W[k * DOUT + c0 + j], acc[j]);
    }
    uint4 st;
    st.x = (unsigned int)f2bf(di * acc[0]) | ((unsigned int)f2bf(di * acc[1]) << 16);
    st.y = (unsigned int)f2bf(di * acc[2]) | ((unsigned int)f2bf(di * acc[3]) << 16);
    st.z = (unsigned int)f2bf(di * acc[4]) | ((unsigned int)f2bf(di * acc[5]) << 16);
    st.w = (unsigned int)f2bf(di * acc[6]) | ((unsigned int)f2bf(di * acc[7]) << 16);
    *(uint4*)(Hs + (size_t)row * DOUT + c0) = st;
  }
}

// ---------------- gather aggregation, one wave per dst node ----------------
// Rows pre-scaled by dinv[src]: agg = dinv[d]*(sum Hs[src] + Hs[d]) -> no
// per-edge weight, 4B edge records, one readlane per edge, add not fma.
// Non-LSM: bf16 store + fused BN partial stats. LSM: +b3, fp32 emb & log_softmax.
template <int DOUT, bool LSM>
__global__ __launch_bounds__(256) void k_agg(const unsigned short* __restrict__ Hs,
                                             const int* __restrict__ rowptr,
                                             const int* __restrict__ edges,
                                             const float* __restrict__ dinv,
                                             const float* __restrict__ bias,
                                             unsigned short* __restrict__ Ab,
                                             float* __restrict__ emb,
                                             float* __restrict__ out,
                                             float* __restrict__ stats, int N) {
  int wid = (blockIdx.x * 256 + threadIdx.x) >> 6;
  int lane = threadIdx.x & 63;
  int wslot = threadIdx.x >> 6;
  int node = __builtin_amdgcn_readfirstlane(wid);
  bool active = node < N;
  float res = 0.0f;
  if (active) {
    int beg = rowptr[node];
    int end = rowptr[node + 1];
    float acc0 = (lane < DOUT) ? bf2f(Hs[(size_t)node * DOUT + lane]) : 0.0f;  // self
    float acc1 = 0.f, acc2 = 0.f, acc3 = 0.f;
    for (int b2 = beg; b2 < end; b2 += 64) {
      int cnt = min(64, end - b2);
      int srcv = edges[b2 + (lane < cnt ? lane : 0)];  // coalesced batch load
      int j = 0;
      for (; j + 8 <= cnt; j += 8) {
        int s0 = __builtin_amdgcn_readlane(srcv, j + 0);
        int s1 = __builtin_amdgcn_readlane(srcv, j + 1);
        int s2 = __builtin_amdgcn_readlane(srcv, j + 2);
        int s3 = __builtin_amdgcn_readlane(srcv, j + 3);
        int s4 = __builtin_amdgcn_readlane(srcv, j + 4);
        int s5 = __builtin_amdgcn_readlane(srcv, j + 5);
        int s6 = __builtin_amdgcn_readlane(srcv, j + 6);
        int s7 = __builtin_amdgcn_readlane(srcv, j + 7);
        float h0 = bf2f(Hs[(size_t)s0 * DOUT + lane]);
        float h1 = bf2f(Hs[(size_t)s1 * DOUT + lane]);
        float h2 = bf2f(Hs[(size_t)s2 * DOUT + lane]);
        float h3 = bf2f(Hs[(size_t)s3 * DOUT + lane]);
        float h4 = bf2f(Hs[(size_t)s4 * DOUT + lane]);
        float h5 = bf2f(Hs[(size_t)s5 * DOUT + lane]);
        float h6 = bf2f(Hs[(size_t)s6 * DOUT + lane]);
        float h7 = bf2f(Hs[(size_t)s7 * DOUT + lane]);
        acc0 += h0; acc1 += h1; acc2 += h2; acc3 += h3;
        acc0 += h4; acc1 += h5; acc2 += h6; acc3 += h7;
      }
      for (; j < cnt; ++j) {
        int s = __builtin_amdgcn_readlane(srcv, j);
        acc0 += bf2f(Hs[(size_t)s * DOUT + lane]);
      }
    }
    res = dinv[node] * ((acc0 + acc1) + (acc2 + acc3));
  }
  if constexpr (!LSM) {
    if (active && lane < DOUT) Ab[(size_t)node * DOUT + lane] = f2bf(res);
    __shared__ float ss[4][64], ss2[4][64];
    ss[wslot][lane] = active ? res : 0.0f;
    ss2[wslot][lane] = active ? res * res : 0.0f;
    __syncthreads();
    if (threadIdx.x < 64) {
      float s = ss[0][lane] + ss[1][lane] + ss[2][lane] + ss[3][lane];
      float s2 = ss2[0][lane] + ss2[1][lane] + ss2[2][lane] + ss2[3][lane];
      int slot = blockIdx.x & (SLOTS - 1);
      atomicAdd(&stats[(size_t)slot * 128 + lane], s);
      atomicAdd(&stats[(size_t)slot * 128 + 64 + lane], s2);
    }
  } else {
    if (!active) return;
    if (lane < DOUT) res += bias[lane];
    float v = (lane < DOUT) ? res : -INFINITY;
    float m = v;
#pragma unroll
    for (int off = 32; off; off >>= 1) m = fmaxf(m, __shfl_xor(m, off));
    float ex = (lane < DOUT) ? expf(v - m) : 0.0f;
    float ssum = ex;
#pragma unroll
    for (int off = 32; off; off >>= 1) ssum += __shfl_xor(ssum, off);
    if (lane < DOUT) {
      emb[(size_t)node * DOUT + lane] = res;
      out[(size_t)node * DOUT + lane] = res - m - logf(ssum);
    }
  }
}

// ---------------- reduce stat partials + fold BN affine into next-layer W ----------------
template <int DOUT>
__global__ __launch_bounds__(256) void k_fold(const float* __restrict__ stats,
                                              const float* __restrict__ g,
                                              const float* __restrict__ be,
                                              const float* __restrict__ W,
                                              float* __restrict__ Wf,
                                              float* __restrict__ brow, float invN) {
  __shared__ float red[128];
  __shared__ float scale[64], shift[64];
  int t = threadIdx.x;
  if (t < 128) {
    float sacc = 0.f;
    for (int b = 0; b < SLOTS; b++) sacc += stats[(size_t)b * 128 + t];
    red[t] = sacc;
  }
  __syncthreads();
  if (t < 64) {
    float mean = red[t] * invN;
    float var = red[64 + t] * invN - mean * mean;
    float sc = g[t] * rsqrtf(var + EPSV);
    scale[t] = sc;
    shift[t] = be[t] - mean * sc;
  }
  __syncthreads();
  for (int i = t; i < 64 * DOUT; i += 256) Wf[i] = scale[i / DOUT] * W[i];
  if (t < DOUT) {
    float acc = 0.f;
    for (int k = 0; k < 64; k++) acc = fmaf(shift[k], W[k * DOUT + t], acc);
    brow[t] = acc;
  }
}

extern "C" void kernel_launch(void* const* d_in, const int* in_sizes, int n_in,
                              void* d_out, int out_size, void* d_ws, size_t ws_size,
                              hipStream_t stream) {
  const float* x = (const float*)d_in[0];
  const int* ei = (const int*)d_in[1];
  const float* W1 = (const float*)d_in[2];
  // b1 = d_in[3], b2 = d_in[5]: cancel exactly inside BatchNorm (mean subtraction)
  const float* W2 = (const float*)d_in[4];
  const float* W3 = (const float*)d_in[6];
  const float* b3 = (const float*)d_in[7];
  const float* g1 = (const float*)d_in[8];
  const float* be1 = (const float*)d_in[9];
  const float* g2 = (const float*)d_in[10];
  const float* be2 = (const float*)d_in[11];

  int N = in_sizes[0] / 64;
  int E = in_sizes[1] / 2;
  const int* src = ei;
  const int* dst = ei + E;
  int NB = (N + 127) / 128;  // 128-node buckets

  char* ws = (char*)d_ws;
  int* gcount = (int*)ws;                           // [NBMAX]   (zeroed)
  float* stats1 = (float*)(gcount + NBMAX);         // [SLOTS*128] (zeroed)
  float* stats2 = stats1 + SLOTS * 128;             // [SLOTS*128] (zeroed)
  float* dinv = stats2 + SLOTS * 128;               // [N]
  int* rowptr = (int*)(dinv + N);                   // [N+1]
  int* bbase = rowptr + (N + 1);                    // [NBMAX]
  float* Wf = (float*)(bbase + NBMAX);              // [64*64]
  float* brow = Wf + 64 * 64;                       // [64]
  unsigned short* Hs =
      (unsigned short*)(((uintptr_t)(brow + 64) + 15) & ~(uintptr_t)15);  // [N*64] bf16
  unsigned short* Ab = Hs + (size_t)N * 64;         // [N*64] bf16
  int* staging = (int*)(Ab + (size_t)N * 64);       // [NBMAX*BCAP]
  int* edges = staging + (size_t)NBMAX * BCAP;      // [E]

  float* out = (float*)d_out;
  float* emb = (float*)d_out + (size_t)N * 40;

  dim3 B(256);
  int gN = (N + 255) / 256;
  int gW = (N + 3) / 4;  // one wave per node, 4 waves per block

  // ---- CSR build (+rowptr+dinv) ----
  hipMemsetAsync(gcount, 0, (NBMAX + 2 * SLOTS * 128) * sizeof(int), stream);
  k_binA<<<(E + 4095) / 4096, B, 0, stream>>>(src, dst, gcount, staging, E, NB);
  k_scanb<<<1, B, 0, stream>>>(gcount, bbase, rowptr, NB, N, E);
  k_binB<<<NB, B, 0, stream>>>(staging, gcount, bbase, rowptr, dinv, edges, N);

  // ---- layer 1 ----
  k_gemm<64, false><<<gN, B, 0, stream>>>(x, W1, nullptr, dinv, Hs, N);
  k_agg<64, false><<<gW, B, 0, stream>>>(Hs, rowptr, edges, dinv, nullptr, Ab, nullptr,
                                         nullptr, stats1, N);
  k_fold<64><<<1, B, 0, stream>>>(stats1, g1, be1, W2, Wf, brow, 1.0f / (float)N);

  // ---- layer 2 ----
  k_gemm<64, true><<<gN, B, 0, stream>>>(Ab, Wf, brow, dinv, Hs, N);
  k_agg<64, false><<<gW, B, 0, stream>>>(Hs, rowptr, edges, dinv, nullptr, Ab, nullptr,
                                         nullptr, stats2, N);
  k_fold<40><<<1, B, 0, stream>>>(stats2, g2, be2, W3, Wf, brow, 1.0f / (float)N);

  // ---- layer 3: gemm -> agg(+b3) -> fused log_softmax ----
  k_gemm<40, true><<<gN, B, 0, stream>>>(Ab, Wf, brow, dinv, Hs, N);
  k_agg<40, true><<<gW, B, 0, stream>>>(Hs, rowptr, edges, dinv, b3, nullptr, emb, out,
                                        nullptr, N);
}

// Round 7
// 391.356 us; speedup vs baseline: 3.4523x; 1.0427x over previous
//
#include <hip/hip_runtime.h>
#include <hip/hip_bf16.h>
#include <math.h>
#include <stdint.h>

#define EPSV 1e-5f
#define BCAP 2560        // bucket capacity: mean 2048, sigma ~45 -> 11 sigma slack
#define NBMAX 1024       // >= ceil(N/128)
#define SLOTS 128        // BN-stat partial slots

static __device__ __forceinline__ float bf_lo(unsigned int u) {
  union { unsigned int i; float f; } v; v.i = u << 16; return v.f;
}
static __device__ __forceinline__ float bf_hi(unsigned int u) {
  union { unsigned int i; float f; } v; v.i = u & 0xffff0000u; return v.f;
}
static __device__ __forceinline__ unsigned short f2bf(float f) {
  union { float f; unsigned int i; } v; v.f = f;
  unsigned int r = v.i + 0x7fff + ((v.i >> 16) & 1);  // RTNE
  return (unsigned short)(r >> 16);
}

// ---------------- phase A: bin edges into 128-node buckets ----------------
// Active write-tail set = NB (~782) lines ~ 50 KB << per-XCD L2 -> lines fill
// before eviction (write amplification ~1). Record: src | d_local<<20.
__global__ __launch_bounds__(256) void k_binA(const int* __restrict__ src,
                                              const int* __restrict__ dst,
                                              int* __restrict__ gcount,
                                              int* __restrict__ staging, int E, int NB) {
  __shared__ int hist[NBMAX];
  __shared__ int gbase[NBMAX];
  int t = threadIdx.x;
  for (int b = t; b < NB; b += 256) hist[b] = 0;
  __syncthreads();
  int e0 = blockIdx.x * 4096;
  int sreg[16], dreg[16];
#pragma unroll
  for (int j = 0; j < 16; j++) {
    int e = e0 + j * 256 + t;
    if (e < E) {
      sreg[j] = src[e];
      dreg[j] = dst[e];
      atomicAdd(&hist[dreg[j] >> 7], 1);
    } else {
      dreg[j] = -1;
    }
  }
  __syncthreads();
  for (int b = t; b < NB; b += 256) {
    int c = hist[b];
    if (c) gbase[b] = b * BCAP + atomicAdd(&gcount[b], c);
    hist[b] = 0;  // reuse as local rank counter
  }
  __syncthreads();
#pragma unroll
  for (int j = 0; j < 16; j++) {
    if (dreg[j] >= 0) {
      int b = dreg[j] >> 7;
      int r = atomicAdd(&hist[b], 1);
      int pos = gbase[b] + r;
      if (pos < (b + 1) * BCAP)  // overflow guard (statistically impossible)
        staging[pos] = sreg[j] | ((dreg[j] & 127) << 20);
    }
  }
}

// ---------------- exclusive scan of gcount -> bucket bases ----------------
__global__ __launch_bounds__(256) void k_scanb(const int* __restrict__ gcount,
                                               int* __restrict__ bbase,
                                               int* __restrict__ rowptr, int NB, int N,
                                               int E) {
  __shared__ int lds[256];
  int t = threadIdx.x;
  int v[4], s = 0;
#pragma unroll
  for (int j = 0; j < 4; j++) {
    int idx = t * 4 + j;
    v[j] = (idx < NB) ? gcount[idx] : 0;
    s += v[j];
  }
  lds[t] = s;
  __syncthreads();
  for (int off = 1; off < 256; off <<= 1) {
    int tv = (t >= off) ? lds[t - off] : 0;
    __syncthreads();
    if (t >= off) lds[t] += tv;
    __syncthreads();
  }
  int run = (t == 0) ? 0 : lds[t - 1];
#pragma unroll
  for (int j = 0; j < 4; j++) {
    int idx = t * 4 + j;
    if (idx < NB) bbase[idx] = run;
    run += v[j];
  }
  if (t == 0) rowptr[N] = E;
}

// ---------------- phase B: bucket -> exact CSR + rowptr + dinv ----------------
__global__ __launch_bounds__(256) void k_binB(const int* __restrict__ staging,
                                              const int* __restrict__ gcount,
                                              const int* __restrict__ bbase,
                                              int* __restrict__ rowptr,
                                              float* __restrict__ dinv,
                                              int* __restrict__ edges, int N) {
  __shared__ int rec[BCAP];
  __shared__ int cnt[128], cur[128], scn[128];
  int b = blockIdx.x;
  int t = threadIdx.x;
  int lo = b * 128;
  int nn = min(128, N - lo);
  int c = min(gcount[b], BCAP);
  if (t < 128) cnt[t] = 0;
  __syncthreads();
  for (int r = t; r < c; r += 256) {
    int x = staging[b * BCAP + r];
    rec[r] = x;
    atomicAdd(&cnt[x >> 20], 1);
  }
  __syncthreads();
  if (t < 128) scn[t] = cnt[t];
  __syncthreads();
  for (int off = 1; off < 128; off <<= 1) {
    int tv = (t < 128 && t >= off) ? scn[t - off] : 0;
    __syncthreads();
    if (t < 128 && t >= off) scn[t] += tv;
    __syncthreads();
  }
  int base = bbase[b];
  if (t < 128) {
    int excl = (t == 0) ? 0 : scn[t - 1];
    cur[t] = excl;
    if (t < nn) {
      rowptr[lo + t] = base + excl;
      dinv[lo + t] = rsqrtf((float)cnt[t] + 1.0f);  // +1 = self loop
    }
  }
  __syncthreads();
  for (int r = t; r < c; r += 256) {
    int x = rec[r];
    int pos = base + atomicAdd(&cur[x >> 20], 1);
    edges[pos] = x & 0xFFFFF;
  }
}

// ---------------- GEMM: Hs[r] = dinv[r] * (X[r] @ W + brow), bf16 out ----------------
template <int DOUT, bool BFIN>
__global__ __launch_bounds__(256) void k_gemm(const void* __restrict__ Xv,
                                              const float* __restrict__ W,
                                              const float* __restrict__ brow,
                                              const float* __restrict__ dinv,
                                              unsigned short* __restrict__ Hs, int N) {
  int row = blockIdx.x * 256 + threadIdx.x;
  if (row >= N) return;
  float xs[64];
  if (BFIN) {
    const uint4* xp = (const uint4*)((const unsigned short*)Xv + (size_t)row * 64);
#pragma unroll
    for (int i = 0; i < 8; i++) {
      uint4 u = xp[i];
      xs[i * 8 + 0] = bf_lo(u.x); xs[i * 8 + 1] = bf_hi(u.x);
      xs[i * 8 + 2] = bf_lo(u.y); xs[i * 8 + 3] = bf_hi(u.y);
      xs[i * 8 + 4] = bf_lo(u.z); xs[i * 8 + 5] = bf_hi(u.z);
      xs[i * 8 + 6] = bf_lo(u.w); xs[i * 8 + 7] = bf_hi(u.w);
    }
  } else {
    const float4* xp = (const float4*)((const float*)Xv + (size_t)row * 64);
#pragma unroll
    for (int i = 0; i < 16; i++) {
      float4 f = xp[i];
      xs[i * 4 + 0] = f.x; xs[i * 4 + 1] = f.y;
      xs[i * 4 + 2] = f.z; xs[i * 4 + 3] = f.w;
    }
  }
  float di = dinv[row];
#pragma unroll 1
  for (int c0 = 0; c0 < DOUT; c0 += 8) {
    float acc[8];
#pragma unroll
    for (int j = 0; j < 8; j++) acc[j] = brow ? brow[c0 + j] : 0.0f;
#pragma unroll
    for (int k = 0; k < 64; k++) {
      float xk = xs[k];
#pragma unroll
      for (int j = 0; j < 8; j++) acc[j] = fmaf(xk, W[k * DOUT + c0 + j], acc[j]);
    }
    uint4 st;
    st.x = (unsigned int)f2bf(di * acc[0]) | ((unsigned int)f2bf(di * acc[1]) << 16);
    st.y = (unsigned int)f2bf(di * acc[2]) | ((unsigned int)f2bf(di * acc[3]) << 16);
    st.z = (unsigned int)f2bf(di * acc[4]) | ((unsigned int)f2bf(di * acc[5]) << 16);
    st.w = (unsigned int)f2bf(di * acc[6]) | ((unsigned int)f2bf(di * acc[7]) << 16);
    *(uint4*)(Hs + (size_t)row * DOUT + c0) = st;
  }
}

// ---------------- gather aggregation, one wave per dst node ----------------
// Dword-packed half-wave scheme: lane owns feature pair (2*f2, 2*f2+1); the
// two wave-halves process two edges at once. ALL __shfl calls execute at
// full exec (they are convergent; sourcing an exec-masked lane is UB — the
// R6 bug); only the gather loads + adds are predicated on fok.
template <int DOUT, bool LSM>
__global__ __launch_bounds__(256) void k_agg(const unsigned int* __restrict__ Hs32,
                                             const int* __restrict__ rowptr,
                                             const int* __restrict__ edges,
                                             const float* __restrict__ dinv,
                                             const float* __restrict__ bias,
                                             unsigned int* __restrict__ Ab32,
                                             float* __restrict__ emb,
                                             float* __restrict__ out,
                                             float* __restrict__ stats, int N) {
  constexpr int RD = DOUT / 2;  // dwords per row
  int wid = (blockIdx.x * 256 + threadIdx.x) >> 6;
  int lane = threadIdx.x & 63;
  int wslot = threadIdx.x >> 6;
  int f2 = lane & 31;
  int half = lane >> 5;
  bool fok = f2 < RD;
  int node = __builtin_amdgcn_readfirstlane(wid);
  bool active = node < N;
  float rLo = 0.f, rHi = 0.f;
  if (active) {
    int beg = rowptr[node];
    int end = rowptr[node + 1];
    float a0Lo = 0.f, a0Hi = 0.f, a1Lo = 0.f, a1Hi = 0.f;
    if (half == 0 && fok) {  // self-loop term
      unsigned int u = Hs32[(unsigned)(node * RD) + f2];
      a0Lo = bf_lo(u);
      a0Hi = bf_hi(u);
    }
    for (int b2 = beg; b2 < end; b2 += 64) {
      int cnt = min(64, end - b2);
      int srcv = edges[b2 + (lane < cnt ? lane : 0)];  // full-exec batch load
      int full = cnt & ~1;
      int j = 0;
      for (; j + 8 <= full; j += 8) {
        int i0 = j + half;
        int s0 = __shfl(srcv, i0);        // full exec — convergent
        int s1 = __shfl(srcv, i0 + 2);
        int s2 = __shfl(srcv, i0 + 4);
        int s3 = __shfl(srcv, i0 + 6);
        if (fok) {                        // divergent loads/adds are fine
          unsigned int u0 = Hs32[(unsigned)(s0 * RD) + f2];
          unsigned int u1 = Hs32[(unsigned)(s1 * RD) + f2];
          unsigned int u2 = Hs32[(unsigned)(s2 * RD) + f2];
          unsigned int u3 = Hs32[(unsigned)(s3 * RD) + f2];
          a0Lo += bf_lo(u0); a0Hi += bf_hi(u0);
          a1Lo += bf_lo(u1); a1Hi += bf_hi(u1);
          a0Lo += bf_lo(u2); a0Hi += bf_hi(u2);
          a1Lo += bf_lo(u3); a1Hi += bf_hi(u3);
        }
      }
      for (; j < full; j += 2) {
        int s0 = __shfl(srcv, j + half);  // full exec
        if (fok) {
          unsigned int u0 = Hs32[(unsigned)(s0 * RD) + f2];
          a0Lo += bf_lo(u0);
          a0Hi += bf_hi(u0);
        }
      }
      if (cnt & 1) {
        int s0 = __shfl(srcv, cnt - 1);   // full exec
        if (half == 0 && fok) {
          unsigned int u0 = Hs32[(unsigned)(s0 * RD) + f2];
          a1Lo += bf_lo(u0);
          a1Hi += bf_hi(u0);
        }
      }
    }
    rLo = a0Lo + a1Lo;
    rHi = a0Hi + a1Hi;
    rLo += __shfl_xor(rLo, 32);  // combine halves (full exec within active wave)
    rHi += __shfl_xor(rHi, 32);
    float dn = dinv[node];
    rLo *= dn;
    rHi *= dn;
  }
  if constexpr (!LSM) {
    // bf16 store (half 0 lanes: 32 dwords = full row, coalesced)
    if (active && half == 0 && fok)
      Ab32[(unsigned)(node * RD) + f2] =
          (unsigned int)f2bf(rLo) | ((unsigned int)f2bf(rHi) << 16);
    __shared__ float ls[4][64], ls2[4][64];
    if (half == 0) {
      float vLo = active ? rLo : 0.f;
      float vHi = active ? rHi : 0.f;
      ls[wslot][2 * f2] = vLo;
      ls[wslot][2 * f2 + 1] = vHi;
      ls2[wslot][2 * f2] = vLo * vLo;
      ls2[wslot][2 * f2 + 1] = vHi * vHi;
    }
    __syncthreads();
    if (threadIdx.x < 64) {
      int t = threadIdx.x;
      float s = ls[0][t] + ls[1][t] + ls[2][t] + ls[3][t];
      float s2 = ls2[0][t] + ls2[1][t] + ls2[2][t] + ls2[3][t];
      int slot = blockIdx.x & (SLOTS - 1);
      atomicAdd(&stats[(size_t)slot * 128 + t], s);
      atomicAdd(&stats[(size_t)slot * 128 + 64 + t], s2);
    }
  } else {
    if (!active) return;  // wave-uniform
    if (fok) {
      rLo += bias[2 * f2];
      rHi += bias[2 * f2 + 1];
    }
    float mx = fok ? fmaxf(rLo, rHi) : -INFINITY;
#pragma unroll
    for (int off = 16; off; off >>= 1) mx = fmaxf(mx, __shfl_xor(mx, off));
    float ex = fok ? (expf(rLo - mx) + expf(rHi - mx)) : 0.0f;
    float ssum = ex;
#pragma unroll
    for (int off = 16; off; off >>= 1) ssum += __shfl_xor(ssum, off);
    float lse = mx + logf(ssum);
    if (half == 0 && fok) {
      *(float2*)(emb + (size_t)node * DOUT + 2 * f2) = make_float2(rLo, rHi);
      *(float2*)(out + (size_t)node * DOUT + 2 * f2) =
          make_float2(rLo - lse, rHi - lse);
    }
  }
}

// ---------------- reduce stat partials + fold BN affine into next-layer W ----------------
template <int DOUT>
__global__ __launch_bounds__(256) void k_fold(const float* __restrict__ stats,
                                              const float* __restrict__ g,
                                              const float* __restrict__ be,
                                              const float* __restrict__ W,
                                              float* __restrict__ Wf,
                                              float* __restrict__ brow, float invN) {
  __shared__ float red[128];
  __shared__ float scale[64], shift[64];
  int t = threadIdx.x;
  if (t < 128) {
    float sacc = 0.f;
    for (int b = 0; b < SLOTS; b++) sacc += stats[(size_t)b * 128 + t];
    red[t] = sacc;
  }
  __syncthreads();
  if (t < 64) {
    float mean = red[t] * invN;
    float var = red[64 + t] * invN - mean * mean;
    float sc = g[t] * rsqrtf(var + EPSV);
    scale[t] = sc;
    shift[t] = be[t] - mean * sc;
  }
  __syncthreads();
  for (int i = t; i < 64 * DOUT; i += 256) Wf[i] = scale[i / DOUT] * W[i];
  if (t < DOUT) {
    float acc = 0.f;
    for (int k = 0; k < 64; k++) acc = fmaf(shift[k], W[k * DOUT + t], acc);
    brow[t] = acc;
  }
}

extern "C" void kernel_launch(void* const* d_in, const int* in_sizes, int n_in,
                              void* d_out, int out_size, void* d_ws, size_t ws_size,
                              hipStream_t stream) {
  const float* x = (const float*)d_in[0];
  const int* ei = (const int*)d_in[1];
  const float* W1 = (const float*)d_in[2];
  // b1 = d_in[3], b2 = d_in[5]: cancel exactly inside BatchNorm (mean subtraction)
  const float* W2 = (const float*)d_in[4];
  const float* W3 = (const float*)d_in[6];
  const float* b3 = (const float*)d_in[7];
  const float* g1 = (const float*)d_in[8];
  const float* be1 = (const float*)d_in[9];
  const float* g2 = (const float*)d_in[10];
  const float* be2 = (const float*)d_in[11];

  int N = in_sizes[0] / 64;
  int E = in_sizes[1] / 2;
  const int* src = ei;
  const int* dst = ei + E;
  int NB = (N + 127) / 128;  // 128-node buckets

  char* ws = (char*)d_ws;
  int* gcount = (int*)ws;                           // [NBMAX]   (zeroed)
  float* stats1 = (float*)(gcount + NBMAX);         // [SLOTS*128] (zeroed)
  float* stats2 = stats1 + SLOTS * 128;             // [SLOTS*128] (zeroed)
  float* dinv = stats2 + SLOTS * 128;               // [N]
  int* rowptr = (int*)(dinv + N);                   // [N+1]
  int* bbase = rowptr + (N + 1);                    // [NBMAX]
  float* Wf = (float*)(bbase + NBMAX);              // [64*64]
  float* brow = Wf + 64 * 64;                       // [64]
  unsigned short* Hs =
      (unsigned short*)(((uintptr_t)(brow + 64) + 15) & ~(uintptr_t)15);  // [N*64] bf16
  unsigned short* Ab = Hs + (size_t)N * 64;         // [N*64] bf16
  int* staging = (int*)(Ab + (size_t)N * 64);       // [NBMAX*BCAP]
  int* edges = staging + (size_t)NBMAX * BCAP;      // [E]

  float* out = (float*)d_out;
  float* emb = (float*)d_out + (size_t)N * 40;

  dim3 B(256);
  int gN = (N + 255) / 256;
  int gW = (N + 3) / 4;  // one wave per node, 4 waves per block

  // ---- CSR build (+rowptr+dinv) ----
  hipMemsetAsync(gcount, 0, (NBMAX + 2 * SLOTS * 128) * sizeof(int), stream);
  k_binA<<<(E + 4095) / 4096, B, 0, stream>>>(src, dst, gcount, staging, E, NB);
  k_scanb<<<1, B, 0, stream>>>(gcount, bbase, rowptr, NB, N, E);
  k_binB<<<NB, B, 0, stream>>>(staging, gcount, bbase, rowptr, dinv, edges, N);

  // ---- layer 1 ----
  k_gemm<64, false><<<gN, B, 0, stream>>>(x, W1, nullptr, dinv, Hs, N);
  k_agg<64, false><<<gW, B, 0, stream>>>((const unsigned int*)Hs, rowptr, edges, dinv,
                                         nullptr, (unsigned int*)Ab, nullptr, nullptr,
                                         stats1, N);
  k_fold<64><<<1, B, 0, stream>>>(stats1, g1, be1, W2, Wf, brow, 1.0f / (float)N);

  // ---- layer 2 ----
  k_gemm<64, true><<<gN, B, 0, stream>>>(Ab, Wf, brow, dinv, Hs, N);
  k_agg<64, false><<<gW, B, 0, stream>>>((const unsigned int*)Hs, rowptr, edges, dinv,
                                         nullptr, (unsigned int*)Ab, nullptr, nullptr,
                                         stats2, N);
  k_fold<40><<<1, B, 0, stream>>>(stats2, g2, be2, W3, Wf, brow, 1.0f / (float)N);

  // ---- layer 3: gemm -> agg(+b3) -> fused log_softmax ----
  k_gemm<40, true><<<gN, B, 0, stream>>>(Ab, Wf, brow, dinv, Hs, N);
  k_agg<40, true><<<gW, B, 0, stream>>>((const unsigned int*)Hs, rowptr, edges, dinv,
                                        b3, nullptr, emb, out, nullptr, N);
}

// Round 8
// 386.976 us; speedup vs baseline: 3.4914x; 1.0113x over previous
//
#include <hip/hip_runtime.h>
#include <hip/hip_bf16.h>
#include <math.h>
#include <stdint.h>

#define EPSV 1e-5f
#define BCAP 2560        // bucket capacity: mean 2048, sigma ~45 -> 11 sigma slack
#define NBMAX 1024       // >= ceil(N/128)
#define SLOTS 128        // BN-stat partial slots
#define NPW 16           // nodes per wave in k_agg (amortize prologue/epilogue)

static __device__ __forceinline__ float bf_lo(unsigned int u) {
  union { unsigned int i; float f; } v; v.i = u << 16; return v.f;
}
static __device__ __forceinline__ float bf_hi(unsigned int u) {
  union { unsigned int i; float f; } v; v.i = u & 0xffff0000u; return v.f;
}
static __device__ __forceinline__ unsigned short f2bf(float f) {
  union { float f; unsigned int i; } v; v.f = f;
  unsigned int r = v.i + 0x7fff + ((v.i >> 16) & 1);  // RTNE
  return (unsigned short)(r >> 16);
}

// ---------------- phase A: bin edges into 128-node buckets ----------------
// Active write-tail set = NB (~782) lines ~ 50 KB << per-XCD L2 -> lines fill
// before eviction (write amplification ~1). Record: src | d_local<<20.
__global__ __launch_bounds__(256) void k_binA(const int* __restrict__ src,
                                              const int* __restrict__ dst,
                                              int* __restrict__ gcount,
                                              int* __restrict__ staging, int E, int NB) {
  __shared__ int hist[NBMAX];
  __shared__ int gbase[NBMAX];
  int t = threadIdx.x;
  for (int b = t; b < NB; b += 256) hist[b] = 0;
  __syncthreads();
  int e0 = blockIdx.x * 4096;
  int sreg[16], dreg[16];
#pragma unroll
  for (int j = 0; j < 16; j++) {
    int e = e0 + j * 256 + t;
    if (e < E) {
      sreg[j] = src[e];
      dreg[j] = dst[e];
      atomicAdd(&hist[dreg[j] >> 7], 1);
    } else {
      dreg[j] = -1;
    }
  }
  __syncthreads();
  for (int b = t; b < NB; b += 256) {
    int c = hist[b];
    if (c) gbase[b] = b * BCAP + atomicAdd(&gcount[b], c);
    hist[b] = 0;  // reuse as local rank counter
  }
  __syncthreads();
#pragma unroll
  for (int j = 0; j < 16; j++) {
    if (dreg[j] >= 0) {
      int b = dreg[j] >> 7;
      int r = atomicAdd(&hist[b], 1);
      int pos = gbase[b] + r;
      if (pos < (b + 1) * BCAP)  // overflow guard (statistically impossible)
        staging[pos] = sreg[j] | ((dreg[j] & 127) << 20);
    }
  }
}

// ---------------- phase B: bucket -> CSR at STATIC base b*BCAP ----------------
// Writes rowseg[node]=(beg,end) directly -> no global scan kernel needed.
__global__ __launch_bounds__(256) void k_binB(const int* __restrict__ staging,
                                              const int* __restrict__ gcount,
                                              int2* __restrict__ rowseg,
                                              float* __restrict__ dinv,
                                              int* __restrict__ edges, int N) {
  __shared__ int rec[BCAP];
  __shared__ int cnt[128], cur[128], scn[128];
  int b = blockIdx.x;
  int t = threadIdx.x;
  int lo = b * 128;
  int nn = min(128, N - lo);
  int c = min(gcount[b], BCAP);
  if (t < 128) cnt[t] = 0;
  __syncthreads();
  for (int r = t; r < c; r += 256) {
    int x = staging[b * BCAP + r];
    rec[r] = x;
    atomicAdd(&cnt[x >> 20], 1);
  }
  __syncthreads();
  if (t < 128) scn[t] = cnt[t];
  __syncthreads();
  for (int off = 1; off < 128; off <<= 1) {
    int tv = (t < 128 && t >= off) ? scn[t - off] : 0;
    __syncthreads();
    if (t < 128 && t >= off) scn[t] += tv;
    __syncthreads();
  }
  int base = b * BCAP;  // static bucket base
  if (t < 128) {
    int excl = (t == 0) ? 0 : scn[t - 1];
    cur[t] = excl;
    if (t < nn) {
      rowseg[lo + t] = make_int2(base + excl, base + excl + cnt[t]);
      dinv[lo + t] = rsqrtf((float)cnt[t] + 1.0f);  // +1 = self loop
    }
  }
  __syncthreads();
  for (int r = t; r < c; r += 256) {
    int x = rec[r];
    int pos = base + atomicAdd(&cur[x >> 20], 1);
    edges[pos] = x & 0xFFFFF;
  }
}

// ---------------- GEMM: Hs[r] = dinv[r] * (X[r] @ W + brow), bf16 out ----------------
template <int DOUT, bool BFIN>
__global__ __launch_bounds__(256) void k_gemm(const void* __restrict__ Xv,
                                              const float* __restrict__ W,
                                              const float* __restrict__ brow,
                                              const float* __restrict__ dinv,
                                              unsigned short* __restrict__ Hs, int N) {
  int row = blockIdx.x * 256 + threadIdx.x;
  if (row >= N) return;
  float xs[64];
  if (BFIN) {
    const uint4* xp = (const uint4*)((const unsigned short*)Xv + (size_t)row * 64);
#pragma unroll
    for (int i = 0; i < 8; i++) {
      uint4 u = xp[i];
      xs[i * 8 + 0] = bf_lo(u.x); xs[i * 8 + 1] = bf_hi(u.x);
      xs[i * 8 + 2] = bf_lo(u.y); xs[i * 8 + 3] = bf_hi(u.y);
      xs[i * 8 + 4] = bf_lo(u.z); xs[i * 8 + 5] = bf_hi(u.z);
      xs[i * 8 + 6] = bf_lo(u.w); xs[i * 8 + 7] = bf_hi(u.w);
    }
  } else {
    const float4* xp = (const float4*)((const float*)Xv + (size_t)row * 64);
#pragma unroll
    for (int i = 0; i < 16; i++) {
      float4 f = xp[i];
      xs[i * 4 + 0] = f.x; xs[i * 4 + 1] = f.y;
      xs[i * 4 + 2] = f.z; xs[i * 4 + 3] = f.w;
    }
  }
  float di = dinv[row];
#pragma unroll 1
  for (int c0 = 0; c0 < DOUT; c0 += 8) {
    float acc[8];
#pragma unroll
    for (int j = 0; j < 8; j++) acc[j] = brow ? brow[c0 + j] : 0.0f;
#pragma unroll
    for (int k = 0; k < 64; k++) {
      float xk = xs[k];
#pragma unroll
      for (int j = 0; j < 8; j++) acc[j] = fmaf(xk, W[k * DOUT + c0 + j], acc[j]);
    }
    uint4 st;
    st.x = (unsigned int)f2bf(di * acc[0]) | ((unsigned int)f2bf(di * acc[1]) << 16);
    st.y = (unsigned int)f2bf(di * acc[2]) | ((unsigned int)f2bf(di * acc[3]) << 16);
    st.z = (unsigned int)f2bf(di * acc[4]) | ((unsigned int)f2bf(di * acc[5]) << 16);
    st.w = (unsigned int)f2bf(di * acc[6]) | ((unsigned int)f2bf(di * acc[7]) << 16);
    *(uint4*)(Hs + (size_t)row * DOUT + c0) = st;
  }
}

// ---------------- gather aggregation, NPW nodes per wave ----------------
// Half-wave dword scheme (R7) + 16 nodes/wave: segments+dinv batch-loaded by
// lanes 0..15 once, SGPR per-node bounds via shfl+readfirstlane, BN stats in
// registers across nodes, single LDS/atomic stats epilogue per wave. All
// __shfl at full exec (convergent; R6 lesson).
template <int DOUT, bool LSM>
__global__ __launch_bounds__(256) void k_agg(const unsigned int* __restrict__ Hs32,
                                             const int2* __restrict__ rowseg,
                                             const int* __restrict__ edges,
                                             const float* __restrict__ dinv,
                                             const float* __restrict__ bias,
                                             unsigned int* __restrict__ Ab32,
                                             float* __restrict__ emb,
                                             float* __restrict__ out,
                                             float* __restrict__ stats, int N) {
  constexpr int RD = DOUT / 2;  // dwords per row
  int wid = (blockIdx.x * 256 + threadIdx.x) >> 6;
  int lane = threadIdx.x & 63;
  int wslot = threadIdx.x >> 6;
  int f2 = lane & 31;
  int half = lane >> 5;
  bool fok = f2 < RD;
  int n0 = __builtin_amdgcn_readfirstlane(wid) * NPW;
  // prologue: lane-parallel per-node segment + dinv loads (once per 16 nodes)
  int segx = 0, segy = 0;
  float dv = 0.f;
  if (lane < NPW && n0 + lane < N) {
    int2 sg = rowseg[n0 + lane];
    segx = sg.x;
    segy = sg.y;
    dv = dinv[n0 + lane];
  }
  float b0 = 0.f, b1 = 0.f;
  if (LSM && fok) { b0 = bias[2 * f2]; b1 = bias[2 * f2 + 1]; }
  float sL = 0.f, sH = 0.f, sL2 = 0.f, sH2 = 0.f;  // BN stats in registers
#pragma unroll 1
  for (int k = 0; k < NPW; k++) {
    int node = n0 + k;
    if (node >= N) break;  // wave-uniform
    int beg = __builtin_amdgcn_readfirstlane(__shfl(segx, k));
    int end = __builtin_amdgcn_readfirstlane(__shfl(segy, k));
    float dn = __shfl(dv, k);
    float a0Lo = 0.f, a0Hi = 0.f, a1Lo = 0.f, a1Hi = 0.f;
    if (half == 0 && fok) {  // self-loop term
      unsigned int u = Hs32[(unsigned)node * RD + f2];
      a0Lo = bf_lo(u);
      a0Hi = bf_hi(u);
    }
    for (int b2 = beg; b2 < end; b2 += 64) {
      int cnt = min(64, end - b2);
      int srcv = edges[b2 + (lane < cnt ? lane : 0)];  // full-exec batch load
      int full = cnt & ~1;
      int j = 0;
      for (; j + 8 <= full; j += 8) {
        int i0 = j + half;
        int s0 = __shfl(srcv, i0);        // full exec — convergent
        int s1 = __shfl(srcv, i0 + 2);
        int s2 = __shfl(srcv, i0 + 4);
        int s3 = __shfl(srcv, i0 + 6);
        if (fok) {
          unsigned int u0 = Hs32[(unsigned)(s0 * RD) + f2];
          unsigned int u1 = Hs32[(unsigned)(s1 * RD) + f2];
          unsigned int u2 = Hs32[(unsigned)(s2 * RD) + f2];
          unsigned int u3 = Hs32[(unsigned)(s3 * RD) + f2];
          a0Lo += bf_lo(u0); a0Hi += bf_hi(u0);
          a1Lo += bf_lo(u1); a1Hi += bf_hi(u1);
          a0Lo += bf_lo(u2); a0Hi += bf_hi(u2);
          a1Lo += bf_lo(u3); a1Hi += bf_hi(u3);
        }
      }
      for (; j < full; j += 2) {
        int s0 = __shfl(srcv, j + half);  // full exec
        if (fok) {
          unsigned int u0 = Hs32[(unsigned)(s0 * RD) + f2];
          a0Lo += bf_lo(u0);
          a0Hi += bf_hi(u0);
        }
      }
      if (cnt & 1) {
        int s0 = __shfl(srcv, cnt - 1);   // full exec
        if (half == 0 && fok) {
          unsigned int u0 = Hs32[(unsigned)(s0 * RD) + f2];
          a1Lo += bf_lo(u0);
          a1Hi += bf_hi(u0);
        }
      }
    }
    float rLo = a0Lo + a1Lo;
    float rHi = a0Hi + a1Hi;
    rLo += __shfl_xor(rLo, 32);  // combine halves — both halves get full sum
    rHi += __shfl_xor(rHi, 32);
    rLo *= dn;
    rHi *= dn;
    if constexpr (!LSM) {
      if (half == 0 && fok)
        Ab32[(unsigned)node * RD + f2] =
            (unsigned int)f2bf(rLo) | ((unsigned int)f2bf(rHi) << 16);
      sL += rLo;                  // register BN stats (rLo=0 for !fok lanes)
      sH += rHi;
      sL2 += rLo * rLo;
      sH2 += rHi * rHi;
    } else {
      rLo += b0;
      rHi += b1;
      float mx = fok ? fmaxf(rLo, rHi) : -INFINITY;
#pragma unroll
      for (int off = 16; off; off >>= 1) mx = fmaxf(mx, __shfl_xor(mx, off));
      float ex = fok ? (expf(rLo - mx) + expf(rHi - mx)) : 0.0f;
      float ssum = ex;
#pragma unroll
      for (int off = 16; off; off >>= 1) ssum += __shfl_xor(ssum, off);
      float lse = mx + logf(ssum);
      if (half == 0 && fok) {
        *(float2*)(emb + (size_t)node * DOUT + 2 * f2) = make_float2(rLo, rHi);
        *(float2*)(out + (size_t)node * DOUT + 2 * f2) =
            make_float2(rLo - lse, rHi - lse);
      }
    }
  }
  if constexpr (!LSM) {
    __shared__ float ls[4][64], ls2[4][64];
    if (half == 0) {
      ls[wslot][2 * f2] = sL;
      ls[wslot][2 * f2 + 1] = sH;
      ls2[wslot][2 * f2] = sL2;
      ls2[wslot][2 * f2 + 1] = sH2;
    }
    __syncthreads();
    if (threadIdx.x < 64) {
      int t = threadIdx.x;
      float s = ls[0][t] + ls[1][t] + ls[2][t] + ls[3][t];
      float s2 = ls2[0][t] + ls2[1][t] + ls2[2][t] + ls2[3][t];
      int slot = blockIdx.x & (SLOTS - 1);
      atomicAdd(&stats[(size_t)slot * 128 + t], s);
      atomicAdd(&stats[(size_t)slot * 128 + 64 + t], s2);
    }
  }
}

// ---------------- reduce stat partials + fold BN affine into next-layer W ----------------
template <int DOUT>
__global__ __launch_bounds__(256) void k_fold(const float* __restrict__ stats,
                                              const float* __restrict__ g,
                                              const float* __restrict__ be,
                                              const float* __restrict__ W,
                                              float* __restrict__ Wf,
                                              float* __restrict__ brow, float invN) {
  __shared__ float red[128];
  __shared__ float scale[64], shift[64];
  int t = threadIdx.x;
  if (t < 128) {
    float sacc = 0.f;
    for (int b = 0; b < SLOTS; b++) sacc += stats[(size_t)b * 128 + t];
    red[t] = sacc;
  }
  __syncthreads();
  if (t < 64) {
    float mean = red[t] * invN;
    float var = red[64 + t] * invN - mean * mean;
    float sc = g[t] * rsqrtf(var + EPSV);
    scale[t] = sc;
    shift[t] = be[t] - mean * sc;
  }
  __syncthreads();
  for (int i = t; i < 64 * DOUT; i += 256) Wf[i] = scale[i / DOUT] * W[i];
  if (t < DOUT) {
    float acc = 0.f;
    for (int k = 0; k < 64; k++) acc = fmaf(shift[k], W[k * DOUT + t], acc);
    brow[t] = acc;
  }
}

extern "C" void kernel_launch(void* const* d_in, const int* in_sizes, int n_in,
                              void* d_out, int out_size, void* d_ws, size_t ws_size,
                              hipStream_t stream) {
  const float* x = (const float*)d_in[0];
  const int* ei = (const int*)d_in[1];
  const float* W1 = (const float*)d_in[2];
  // b1 = d_in[3], b2 = d_in[5]: cancel exactly inside BatchNorm (mean subtraction)
  const float* W2 = (const float*)d_in[4];
  const float* W3 = (const float*)d_in[6];
  const float* b3 = (const float*)d_in[7];
  const float* g1 = (const float*)d_in[8];
  const float* be1 = (const float*)d_in[9];
  const float* g2 = (const float*)d_in[10];
  const float* be2 = (const float*)d_in[11];

  int N = in_sizes[0] / 64;
  int E = in_sizes[1] / 2;
  const int* src = ei;
  const int* dst = ei + E;
  int NB = (N + 127) / 128;  // 128-node buckets

  char* ws = (char*)d_ws;
  int* gcount = (int*)ws;                           // [NBMAX]   (zeroed)
  float* stats1 = (float*)(gcount + NBMAX);         // [SLOTS*128] (zeroed)
  float* stats2 = stats1 + SLOTS * 128;             // [SLOTS*128] (zeroed)
  float* dinv = stats2 + SLOTS * 128;               // [N]
  int2* rowseg = (int2*)(dinv + N);                 // [N] (beg,end)
  float* Wf = (float*)(rowseg + N);                 // [64*64]
  float* brow = Wf + 64 * 64;                       // [64]
  unsigned short* Hs =
      (unsigned short*)(((uintptr_t)(brow + 64) + 15) & ~(uintptr_t)15);  // [N*64] bf16
  unsigned short* Ab = Hs + (size_t)N * 64;         // [N*64] bf16
  int* edges = (int*)(Ab + (size_t)N * 64);         // [NBMAX*BCAP] bucket-strided
  int* staging = (int*)Hs;  // [NBMAX*BCAP] aliases Hs/Ab (consumed before gemm1)

  float* out = (float*)d_out;
  float* emb = (float*)d_out + (size_t)N * 40;

  dim3 B(256);
  int gN = (N + 255) / 256;
  int nwave = (N + NPW - 1) / NPW;
  int gW = (nwave + 3) / 4;  // 4 waves per block

  // ---- CSR build (+rowseg+dinv) ----
  hipMemsetAsync(gcount, 0, (NBMAX + 2 * SLOTS * 128) * sizeof(int), stream);
  k_binA<<<(E + 4095) / 4096, B, 0, stream>>>(src, dst, gcount, staging, E, NB);
  k_binB<<<NB, B, 0, stream>>>(staging, gcount, rowseg, dinv, edges, N);

  // ---- layer 1 ----
  k_gemm<64, false><<<gN, B, 0, stream>>>(x, W1, nullptr, dinv, Hs, N);
  k_agg<64, false><<<gW, B, 0, stream>>>((const unsigned int*)Hs, rowseg, edges, dinv,
                                         nullptr, (unsigned int*)Ab, nullptr, nullptr,
                                         stats1, N);
  k_fold<64><<<1, B, 0, stream>>>(stats1, g1, be1, W2, Wf, brow, 1.0f / (float)N);

  // ---- layer 2 ----
  k_gemm<64, true><<<gN, B, 0, stream>>>(Ab, Wf, brow, dinv, Hs, N);
  k_agg<64, false><<<gW, B, 0, stream>>>((const unsigned int*)Hs, rowseg, edges, dinv,
                                         nullptr, (unsigned int*)Ab, nullptr, nullptr,
                                         stats2, N);
  k_fold<40><<<1, B, 0, stream>>>(stats2, g2, be2, W3, Wf, brow, 1.0f / (float)N);

  // ---- layer 3: gemm -> agg(+b3) -> fused log_softmax ----
  k_gemm<40, true><<<gN, B, 0, stream>>>(Ab, Wf, brow, dinv, Hs, N);
  k_agg<40, true><<<gW, B, 0, stream>>>((const unsigned int*)Hs, rowseg, edges, dinv,
                                        b3, nullptr, emb, out, nullptr, N);
}

// Round 9
// 345.915 us; speedup vs baseline: 3.9058x; 1.1187x over previous
//
#include <hip/hip_runtime.h>
#include <hip/hip_bf16.h>
#include <math.h>
#include <stdint.h>

#define EPSV 1e-5f
#define BCAP 2560        // bucket capacity: mean 2048, sigma ~45 -> 11 sigma slack
#define NBMAX 1024       // >= ceil(N/128)
#define SLOTS 128        // BN-stat partial slots

static __device__ __forceinline__ float bf_lo(unsigned int u) {
  union { unsigned int i; float f; } v; v.i = u << 16; return v.f;
}
static __device__ __forceinline__ float bf_hi(unsigned int u) {
  union { unsigned int i; float f; } v; v.i = u & 0xffff0000u; return v.f;
}
static __device__ __forceinline__ unsigned short f2bf(float f) {
  union { float f; unsigned int i; } v; v.f = f;
  unsigned int r = v.i + 0x7fff + ((v.i >> 16) & 1);  // RTNE
  return (unsigned short)(r >> 16);
}

// ---------------- phase A: bin edges into 128-node buckets ----------------
// Active write-tail set = NB (~782) lines ~ 50 KB << per-XCD L2 -> lines fill
// before eviction (write amplification ~1). Record: src | d_local<<20.
__global__ __launch_bounds__(256) void k_binA(const int* __restrict__ src,
                                              const int* __restrict__ dst,
                                              int* __restrict__ gcount,
                                              int* __restrict__ staging, int E, int NB) {
  __shared__ int hist[NBMAX];
  __shared__ int gbase[NBMAX];
  int t = threadIdx.x;
  for (int b = t; b < NB; b += 256) hist[b] = 0;
  __syncthreads();
  int e0 = blockIdx.x * 4096;
  int sreg[16], dreg[16];
#pragma unroll
  for (int j = 0; j < 16; j++) {
    int e = e0 + j * 256 + t;
    if (e < E) {
      sreg[j] = src[e];
      dreg[j] = dst[e];
      atomicAdd(&hist[dreg[j] >> 7], 1);
    } else {
      dreg[j] = -1;
    }
  }
  __syncthreads();
  for (int b = t; b < NB; b += 256) {
    int c = hist[b];
    if (c) gbase[b] = b * BCAP + atomicAdd(&gcount[b], c);
    hist[b] = 0;  // reuse as local rank counter
  }
  __syncthreads();
#pragma unroll
  for (int j = 0; j < 16; j++) {
    if (dreg[j] >= 0) {
      int b = dreg[j] >> 7;
      int r = atomicAdd(&hist[b], 1);
      int pos = gbase[b] + r;
      if (pos < (b + 1) * BCAP)  // overflow guard (statistically impossible)
        staging[pos] = sreg[j] | ((dreg[j] & 127) << 20);
    }
  }
}

// ---------------- phase B: bucket -> CSR at STATIC base b*BCAP ----------------
// Writes rowseg[node]=(beg,end) directly -> no global scan kernel needed.
__global__ __launch_bounds__(256) void k_binB(const int* __restrict__ staging,
                                              const int* __restrict__ gcount,
                                              int2* __restrict__ rowseg,
                                              float* __restrict__ dinv,
                                              int* __restrict__ edges, int N) {
  __shared__ int rec[BCAP];
  __shared__ int cnt[128], cur[128], scn[128];
  int b = blockIdx.x;
  int t = threadIdx.x;
  int lo = b * 128;
  int nn = min(128, N - lo);
  int c = min(gcount[b], BCAP);
  if (t < 128) cnt[t] = 0;
  __syncthreads();
  for (int r = t; r < c; r += 256) {
    int x = staging[b * BCAP + r];
    rec[r] = x;
    atomicAdd(&cnt[x >> 20], 1);
  }
  __syncthreads();
  if (t < 128) scn[t] = cnt[t];
  __syncthreads();
  for (int off = 1; off < 128; off <<= 1) {
    int tv = (t < 128 && t >= off) ? scn[t - off] : 0;
    __syncthreads();
    if (t < 128 && t >= off) scn[t] += tv;
    __syncthreads();
  }
  int base = b * BCAP;  // static bucket base
  if (t < 128) {
    int excl = (t == 0) ? 0 : scn[t - 1];
    cur[t] = excl;
    if (t < nn) {
      rowseg[lo + t] = make_int2(base + excl, base + excl + cnt[t]);
      dinv[lo + t] = rsqrtf((float)cnt[t] + 1.0f);  // +1 = self loop
    }
  }
  __syncthreads();
  for (int r = t; r < c; r += 256) {
    int x = rec[r];
    int pos = base + atomicAdd(&cur[x >> 20], 1);
    edges[pos] = x & 0xFFFFF;
  }
}

// ---------------- GEMM (+ fused BN fold): Hs[r] = dinv[r]*(Xn[r] @ Wf + brow) ----------------
// FOLD: reduce stat partials in LDS, scale folded into xs[k], brow (shift@W)
// computed per block — replaces the separate 1-block k_fold kernel.
template <int DOUT, bool BFIN, bool FOLD>
__global__ __launch_bounds__(256) void k_gemm(const void* __restrict__ Xv,
                                              const float* __restrict__ W,
                                              const float* __restrict__ stats,
                                              const float* __restrict__ g,
                                              const float* __restrict__ be,
                                              const float* __restrict__ dinv,
                                              unsigned short* __restrict__ Hs, int N,
                                              float invN) {
  __shared__ float red[128];
  __shared__ float scale[64], shift[64], browS[64];
  int t = threadIdx.x;
  if constexpr (FOLD) {
    if (t < 128) {
      float s = 0.f;
      for (int b = 0; b < SLOTS; b++) s += stats[(size_t)b * 128 + t];
      red[t] = s;
    }
    __syncthreads();
    if (t < 64) {
      float mean = red[t] * invN;
      float var = red[64 + t] * invN - mean * mean;
      float sc = g[t] * rsqrtf(var + EPSV);
      scale[t] = sc;
      shift[t] = be[t] - mean * sc;
    }
    __syncthreads();
    if (t < DOUT) {
      float a = 0.f;
      for (int k = 0; k < 64; k++) a = fmaf(shift[k], W[k * DOUT + t], a);
      browS[t] = a;
    }
    __syncthreads();
  }
  int row = blockIdx.x * 256 + t;
  if (row >= N) return;
  float xs[64];
  if constexpr (BFIN) {
    const uint4* xp = (const uint4*)((const unsigned short*)Xv + (size_t)row * 64);
#pragma unroll
    for (int i = 0; i < 8; i++) {
      uint4 u = xp[i];
      xs[i * 8 + 0] = bf_lo(u.x); xs[i * 8 + 1] = bf_hi(u.x);
      xs[i * 8 + 2] = bf_lo(u.y); xs[i * 8 + 3] = bf_hi(u.y);
      xs[i * 8 + 4] = bf_lo(u.z); xs[i * 8 + 5] = bf_hi(u.z);
      xs[i * 8 + 6] = bf_lo(u.w); xs[i * 8 + 7] = bf_hi(u.w);
    }
  } else {
    const float4* xp = (const float4*)((const float*)Xv + (size_t)row * 64);
#pragma unroll
    for (int i = 0; i < 16; i++) {
      float4 f = xp[i];
      xs[i * 4 + 0] = f.x; xs[i * 4 + 1] = f.y;
      xs[i * 4 + 2] = f.z; xs[i * 4 + 3] = f.w;
    }
  }
  if constexpr (FOLD) {
#pragma unroll
    for (int k = 0; k < 64; k++) xs[k] *= scale[k];  // LDS broadcast, conflict-free
  }
  float di = dinv[row];
#pragma unroll 1
  for (int c0 = 0; c0 < DOUT; c0 += 8) {
    float acc[8];
#pragma unroll
    for (int j = 0; j < 8; j++) acc[j] = FOLD ? browS[c0 + j] : 0.0f;
#pragma unroll
    for (int k = 0; k < 64; k++) {
      float xk = xs[k];
#pragma unroll
      for (int j = 0; j < 8; j++) acc[j] = fmaf(xk, W[k * DOUT + c0 + j], acc[j]);
    }
    uint4 st;
    st.x = (unsigned int)f2bf(di * acc[0]) | ((unsigned int)f2bf(di * acc[1]) << 16);
    st.y = (unsigned int)f2bf(di * acc[2]) | ((unsigned int)f2bf(di * acc[3]) << 16);
    st.z = (unsigned int)f2bf(di * acc[4]) | ((unsigned int)f2bf(di * acc[5]) << 16);
    st.w = (unsigned int)f2bf(di * acc[6]) | ((unsigned int)f2bf(di * acc[7]) << 16);
    *(uint4*)(Hs + (size_t)row * DOUT + c0) = st;
  }
}

// ---------------- gather aggregation, ONE wave per dst node (R8 lesson: many
// short waves beat few long ones — per-node chains are serial). Half-wave
// dword scheme; 16-edge unroll tier = 8 outstanding gathers for the dominant
// deg~16 node. All __shfl at full exec (convergent; R6 lesson).
template <int DOUT, bool LSM>
__global__ __launch_bounds__(256) void k_agg(const unsigned int* __restrict__ Hs32,
                                             const int2* __restrict__ rowseg,
                                             const int* __restrict__ edges,
                                             const float* __restrict__ dinv,
                                             const float* __restrict__ bias,
                                             unsigned int* __restrict__ Ab32,
                                             float* __restrict__ emb,
                                             float* __restrict__ out,
                                             float* __restrict__ stats, int N) {
  constexpr int RD = DOUT / 2;  // dwords per row
  int wid = (blockIdx.x * 256 + threadIdx.x) >> 6;
  int lane = threadIdx.x & 63;
  int wslot = threadIdx.x >> 6;
  int f2 = lane & 31;
  int half = lane >> 5;
  bool fok = f2 < RD;
  int node = __builtin_amdgcn_readfirstlane(wid);
  bool active = node < N;
  float rLo = 0.f, rHi = 0.f;
  if (active) {
    int2 sg = rowseg[node];
    int beg = sg.x, end = sg.y;
    float a0Lo = 0.f, a0Hi = 0.f, a1Lo = 0.f, a1Hi = 0.f;
    float a2Lo = 0.f, a2Hi = 0.f, a3Lo = 0.f, a3Hi = 0.f;
    if (half == 0 && fok) {  // self-loop term
      unsigned int u = Hs32[(unsigned)node * RD + f2];
      a0Lo = bf_lo(u);
      a0Hi = bf_hi(u);
    }
    for (int b2 = beg; b2 < end; b2 += 64) {
      int cnt = min(64, end - b2);
      int srcv = edges[b2 + (lane < cnt ? lane : 0)];  // full-exec batch load
      int full = cnt & ~1;
      int j = 0;
      for (; j + 16 <= full; j += 16) {  // 8 outstanding gathers
        int i0 = j + half;
        int s0 = __shfl(srcv, i0);
        int s1 = __shfl(srcv, i0 + 2);
        int s2 = __shfl(srcv, i0 + 4);
        int s3 = __shfl(srcv, i0 + 6);
        int s4 = __shfl(srcv, i0 + 8);
        int s5 = __shfl(srcv, i0 + 10);
        int s6 = __shfl(srcv, i0 + 12);
        int s7 = __shfl(srcv, i0 + 14);
        if (fok) {
          unsigned int u0 = Hs32[(unsigned)(s0 * RD) + f2];
          unsigned int u1 = Hs32[(unsigned)(s1 * RD) + f2];
          unsigned int u2 = Hs32[(unsigned)(s2 * RD) + f2];
          unsigned int u3 = Hs32[(unsigned)(s3 * RD) + f2];
          unsigned int u4 = Hs32[(unsigned)(s4 * RD) + f2];
          unsigned int u5 = Hs32[(unsigned)(s5 * RD) + f2];
          unsigned int u6 = Hs32[(unsigned)(s6 * RD) + f2];
          unsigned int u7 = Hs32[(unsigned)(s7 * RD) + f2];
          a0Lo += bf_lo(u0); a0Hi += bf_hi(u0);
          a1Lo += bf_lo(u1); a1Hi += bf_hi(u1);
          a2Lo += bf_lo(u2); a2Hi += bf_hi(u2);
          a3Lo += bf_lo(u3); a3Hi += bf_hi(u3);
          a0Lo += bf_lo(u4); a0Hi += bf_hi(u4);
          a1Lo += bf_lo(u5); a1Hi += bf_hi(u5);
          a2Lo += bf_lo(u6); a2Hi += bf_hi(u6);
          a3Lo += bf_lo(u7); a3Hi += bf_hi(u7);
        }
      }
      for (; j + 8 <= full; j += 8) {
        int i0 = j + half;
        int s0 = __shfl(srcv, i0);
        int s1 = __shfl(srcv, i0 + 2);
        int s2 = __shfl(srcv, i0 + 4);
        int s3 = __shfl(srcv, i0 + 6);
        if (fok) {
          unsigned int u0 = Hs32[(unsigned)(s0 * RD) + f2];
          unsigned int u1 = Hs32[(unsigned)(s1 * RD) + f2];
          unsigned int u2 = Hs32[(unsigned)(s2 * RD) + f2];
          unsigned int u3 = Hs32[(unsigned)(s3 * RD) + f2];
          a0Lo += bf_lo(u0); a0Hi += bf_hi(u0);
          a1Lo += bf_lo(u1); a1Hi += bf_hi(u1);
          a2Lo += bf_lo(u2); a2Hi += bf_hi(u2);
          a3Lo += bf_lo(u3); a3Hi += bf_hi(u3);
        }
      }
      for (; j < full; j += 2) {
        int s0 = __shfl(srcv, j + half);
        if (fok) {
          unsigned int u0 = Hs32[(unsigned)(s0 * RD) + f2];
          a0Lo += bf_lo(u0);
          a0Hi += bf_hi(u0);
        }
      }
      if (cnt & 1) {
        int s0 = __shfl(srcv, cnt - 1);
        if (half == 0 && fok) {
          unsigned int u0 = Hs32[(unsigned)(s0 * RD) + f2];
          a1Lo += bf_lo(u0);
          a1Hi += bf_hi(u0);
        }
      }
    }
    rLo = (a0Lo + a1Lo) + (a2Lo + a3Lo);
    rHi = (a0Hi + a1Hi) + (a2Hi + a3Hi);
    rLo += __shfl_xor(rLo, 32);  // combine halves
    rHi += __shfl_xor(rHi, 32);
    float dn = dinv[node];
    rLo *= dn;
    rHi *= dn;
  }
  if constexpr (!LSM) {
    if (active && half == 0 && fok)
      Ab32[(unsigned)node * RD + f2] =
          (unsigned int)f2bf(rLo) | ((unsigned int)f2bf(rHi) << 16);
    __shared__ float ls[4][64], ls2[4][64];
    if (half == 0) {
      float vLo = (active && fok) ? rLo : 0.f;
      float vHi = (active && fok) ? rHi : 0.f;
      ls[wslot][2 * f2] = vLo;
      ls[wslot][2 * f2 + 1] = vHi;
      ls2[wslot][2 * f2] = vLo * vLo;
      ls2[wslot][2 * f2 + 1] = vHi * vHi;
    }
    __syncthreads();
    if (threadIdx.x < 64) {
      int t = threadIdx.x;
      float s = ls[0][t] + ls[1][t] + ls[2][t] + ls[3][t];
      float s2 = ls2[0][t] + ls2[1][t] + ls2[2][t] + ls2[3][t];
      int slot = blockIdx.x & (SLOTS - 1);
      atomicAdd(&stats[(size_t)slot * 128 + t], s);
      atomicAdd(&stats[(size_t)slot * 128 + 64 + t], s2);
    }
  } else {
    if (!active) return;  // wave-uniform
    if (fok) {
      rLo += bias[2 * f2];
      rHi += bias[2 * f2 + 1];
    }
    float mx = fok ? fmaxf(rLo, rHi) : -INFINITY;
#pragma unroll
    for (int off = 16; off; off >>= 1) mx = fmaxf(mx, __shfl_xor(mx, off));
    float ex = fok ? (expf(rLo - mx) + expf(rHi - mx)) : 0.0f;
    float ssum = ex;
#pragma unroll
    for (int off = 16; off; off >>= 1) ssum += __shfl_xor(ssum, off);
    float lse = mx + logf(ssum);
    if (half == 0 && fok) {
      *(float2*)(emb + (size_t)node * DOUT + 2 * f2) = make_float2(rLo, rHi);
      *(float2*)(out + (size_t)node * DOUT + 2 * f2) =
          make_float2(rLo - lse, rHi - lse);
    }
  }
}

extern "C" void kernel_launch(void* const* d_in, const int* in_sizes, int n_in,
                              void* d_out, int out_size, void* d_ws, size_t ws_size,
                              hipStream_t stream) {
  const float* x = (const float*)d_in[0];
  const int* ei = (const int*)d_in[1];
  const float* W1 = (const float*)d_in[2];
  // b1 = d_in[3], b2 = d_in[5]: cancel exactly inside BatchNorm (mean subtraction)
  const float* W2 = (const float*)d_in[4];
  const float* W3 = (const float*)d_in[6];
  const float* b3 = (const float*)d_in[7];
  const float* g1 = (const float*)d_in[8];
  const float* be1 = (const float*)d_in[9];
  const float* g2 = (const float*)d_in[10];
  const float* be2 = (const float*)d_in[11];

  int N = in_sizes[0] / 64;
  int E = in_sizes[1] / 2;
  const int* src = ei;
  const int* dst = ei + E;
  int NB = (N + 127) / 128;  // 128-node buckets
  float invN = 1.0f / (float)N;

  char* ws = (char*)d_ws;
  int* gcount = (int*)ws;                           // [NBMAX]   (zeroed)
  float* stats1 = (float*)(gcount + NBMAX);         // [SLOTS*128] (zeroed)
  float* stats2 = stats1 + SLOTS * 128;             // [SLOTS*128] (zeroed)
  float* dinv = stats2 + SLOTS * 128;               // [N]
  int2* rowseg = (int2*)(dinv + N);                 // [N] (beg,end)
  unsigned short* Hs =
      (unsigned short*)(((uintptr_t)(rowseg + N) + 15) & ~(uintptr_t)15);  // [N*64] bf16
  unsigned short* Ab = Hs + (size_t)N * 64;         // [N*64] bf16
  int* edges = (int*)(Ab + (size_t)N * 64);         // [NBMAX*BCAP] bucket-strided
  int* staging = (int*)Hs;  // [NBMAX*BCAP] aliases Hs/Ab (consumed before gemm1)

  float* out = (float*)d_out;
  float* emb = (float*)d_out + (size_t)N * 40;

  dim3 B(256);
  int gN = (N + 255) / 256;
  int gW = (N + 3) / 4;  // one wave per node, 4 waves per block

  // ---- CSR build (+rowseg+dinv) ----
  hipMemsetAsync(gcount, 0, (NBMAX + 2 * SLOTS * 128) * sizeof(int), stream);
  k_binA<<<(E + 4095) / 4096, B, 0, stream>>>(src, dst, gcount, staging, E, NB);
  k_binB<<<NB, B, 0, stream>>>(staging, gcount, rowseg, dinv, edges, N);

  // ---- layer 1 ----
  k_gemm<64, false, false><<<gN, B, 0, stream>>>(x, W1, nullptr, nullptr, nullptr,
                                                 dinv, Hs, N, invN);
  k_agg<64, false><<<gW, B, 0, stream>>>((const unsigned int*)Hs, rowseg, edges, dinv,
                                         nullptr, (unsigned int*)Ab, nullptr, nullptr,
                                         stats1, N);

  // ---- layer 2 (BN1 fold fused into gemm) ----
  k_gemm<64, true, true><<<gN, B, 0, stream>>>(Ab, W2, stats1, g1, be1, dinv, Hs, N,
                                               invN);
  k_agg<64, false><<<gW, B, 0, stream>>>((const unsigned int*)Hs, rowseg, edges, dinv,
                                         nullptr, (unsigned int*)Ab, nullptr, nullptr,
                                         stats2, N);

  // ---- layer 3 (BN2 fold fused): gemm -> agg(+b3) -> fused log_softmax ----
  k_gemm<40, true, true><<<gN, B, 0, stream>>>(Ab, W3, stats2, g2, be2, dinv, Hs, N,
                                               invN);
  k_agg<40, true><<<gW, B, 0, stream>>>((const unsigned int*)Hs, rowseg, edges, dinv,
                                        b3, nullptr, emb, out, nullptr, N);
}

// Round 10
// 343.236 us; speedup vs baseline: 3.9363x; 1.0078x over previous
//
#include <hip/hip_runtime.h>
#include <hip/hip_bf16.h>
#include <math.h>
#include <stdint.h>

#define EPSV 1e-5f
#define BCAP 2560        // bucket capacity: mean 2048, sigma ~45 -> 11 sigma slack
#define NBMAX 1024       // >= ceil(N/128)
#define SLOTS 32         // BN-stat partial slots

static __device__ __forceinline__ float bf_lo(unsigned int u) {
  union { unsigned int i; float f; } v; v.i = u << 16; return v.f;
}
static __device__ __forceinline__ float bf_hi(unsigned int u) {
  union { unsigned int i; float f; } v; v.i = u & 0xffff0000u; return v.f;
}
static __device__ __forceinline__ unsigned short f2bf(float f) {
  union { float f; unsigned int i; } v; v.f = f;
  unsigned int r = v.i + 0x7fff + ((v.i >> 16) & 1);  // RTNE
  return (unsigned short)(r >> 16);
}

// ---------------- phase A: bin edges into 128-node buckets ----------------
// Active write-tail set = NB (~782) lines ~ 50 KB << per-XCD L2 -> lines fill
// before eviction (write amplification ~1). Record: src | d_local<<20.
__global__ __launch_bounds__(256) void k_binA(const int* __restrict__ src,
                                              const int* __restrict__ dst,
                                              int* __restrict__ gcount,
                                              int* __restrict__ staging, int E, int NB) {
  __shared__ int hist[NBMAX];
  __shared__ int gbase[NBMAX];
  int t = threadIdx.x;
  for (int b = t; b < NB; b += 256) hist[b] = 0;
  __syncthreads();
  int e0 = blockIdx.x * 4096;
  int sreg[16], dreg[16];
#pragma unroll
  for (int j = 0; j < 16; j++) {
    int e = e0 + j * 256 + t;
    if (e < E) {
      sreg[j] = src[e];
      dreg[j] = dst[e];
      atomicAdd(&hist[dreg[j] >> 7], 1);
    } else {
      dreg[j] = -1;
    }
  }
  __syncthreads();
  for (int b = t; b < NB; b += 256) {
    int c = hist[b];
    if (c) gbase[b] = b * BCAP + atomicAdd(&gcount[b], c);
    hist[b] = 0;  // reuse as local rank counter
  }
  __syncthreads();
#pragma unroll
  for (int j = 0; j < 16; j++) {
    if (dreg[j] >= 0) {
      int b = dreg[j] >> 7;
      int r = atomicAdd(&hist[b], 1);
      int pos = gbase[b] + r;
      if (pos < (b + 1) * BCAP)  // overflow guard (statistically impossible)
        staging[pos] = sreg[j] | ((dreg[j] & 127) << 20);
    }
  }
}

// ---------------- phase B: bucket -> CSR at STATIC base b*BCAP ----------------
// Writes rowseg[node]=(beg,end) directly -> no global scan kernel needed.
__global__ __launch_bounds__(256) void k_binB(const int* __restrict__ staging,
                                              const int* __restrict__ gcount,
                                              int2* __restrict__ rowseg,
                                              float* __restrict__ dinv,
                                              int* __restrict__ edges, int N) {
  __shared__ int rec[BCAP];
  __shared__ int cnt[128], cur[128], scn[128];
  int b = blockIdx.x;
  int t = threadIdx.x;
  int lo = b * 128;
  int nn = min(128, N - lo);
  int c = min(gcount[b], BCAP);
  if (t < 128) cnt[t] = 0;
  __syncthreads();
  for (int r = t; r < c; r += 256) {
    int x = staging[b * BCAP + r];
    rec[r] = x;
    atomicAdd(&cnt[x >> 20], 1);
  }
  __syncthreads();
  if (t < 128) scn[t] = cnt[t];
  __syncthreads();
  for (int off = 1; off < 128; off <<= 1) {
    int tv = (t < 128 && t >= off) ? scn[t - off] : 0;
    __syncthreads();
    if (t < 128 && t >= off) scn[t] += tv;
    __syncthreads();
  }
  int base = b * BCAP;  // static bucket base
  if (t < 128) {
    int excl = (t == 0) ? 0 : scn[t - 1];
    cur[t] = excl;
    if (t < nn) {
      rowseg[lo + t] = make_int2(base + excl, base + excl + cnt[t]);
      dinv[lo + t] = rsqrtf((float)cnt[t] + 1.0f);  // +1 = self loop
    }
  }
  __syncthreads();
  for (int r = t; r < c; r += 256) {
    int x = rec[r];
    int pos = base + atomicAdd(&cur[x >> 20], 1);
    edges[pos] = x & 0xFFFFF;
  }
}

// ---------------- GEMM (+ fused BN fold): Hs[r] = dinv[r]*(Xn[r] @ Wf + brow) ----------------
// FOLD: reduce stat partials in LDS, scale folded into xs[k], brow (shift@W)
// computed per block. zstats: block 0 zeroes the NEXT layer's stat buffer
// (replaces a memset dispatch; safe — consumer is a later dispatch).
template <int DOUT, bool BFIN, bool FOLD>
__global__ __launch_bounds__(256) void k_gemm(const void* __restrict__ Xv,
                                              const float* __restrict__ W,
                                              const float* __restrict__ stats,
                                              const float* __restrict__ g,
                                              const float* __restrict__ be,
                                              const float* __restrict__ dinv,
                                              unsigned short* __restrict__ Hs,
                                              float* __restrict__ zstats, int N,
                                              float invN) {
  __shared__ float red[128];
  __shared__ float scale[64], shift[64], browS[64];
  int t = threadIdx.x;
  if (zstats && blockIdx.x == 0) {
    for (int i = t; i < SLOTS * 128; i += 256) zstats[i] = 0.f;
  }
  if constexpr (FOLD) {
    if (t < 128) {
      float s = 0.f;
      for (int b = 0; b < SLOTS; b++) s += stats[(size_t)b * 128 + t];
      red[t] = s;
    }
    __syncthreads();
    if (t < 64) {
      float mean = red[t] * invN;
      float var = red[64 + t] * invN - mean * mean;
      float sc = g[t] * rsqrtf(var + EPSV);
      scale[t] = sc;
      shift[t] = be[t] - mean * sc;
    }
    __syncthreads();
    if (t < DOUT) {
      float a = 0.f;
      for (int k = 0; k < 64; k++) a = fmaf(shift[k], W[k * DOUT + t], a);
      browS[t] = a;
    }
    __syncthreads();
  }
  int row = blockIdx.x * 256 + t;
  if (row >= N) return;
  float xs[64];
  if constexpr (BFIN) {
    const uint4* xp = (const uint4*)((const unsigned short*)Xv + (size_t)row * 64);
#pragma unroll
    for (int i = 0; i < 8; i++) {
      uint4 u = xp[i];
      xs[i * 8 + 0] = bf_lo(u.x); xs[i * 8 + 1] = bf_hi(u.x);
      xs[i * 8 + 2] = bf_lo(u.y); xs[i * 8 + 3] = bf_hi(u.y);
      xs[i * 8 + 4] = bf_lo(u.z); xs[i * 8 + 5] = bf_hi(u.z);
      xs[i * 8 + 6] = bf_lo(u.w); xs[i * 8 + 7] = bf_hi(u.w);
    }
  } else {
    const float4* xp = (const float4*)((const float*)Xv + (size_t)row * 64);
#pragma unroll
    for (int i = 0; i < 16; i++) {
      float4 f = xp[i];
      xs[i * 4 + 0] = f.x; xs[i * 4 + 1] = f.y;
      xs[i * 4 + 2] = f.z; xs[i * 4 + 3] = f.w;
    }
  }
  if constexpr (FOLD) {
#pragma unroll
    for (int k = 0; k < 64; k++) xs[k] *= scale[k];  // LDS broadcast, conflict-free
  }
  float di = dinv[row];
#pragma unroll 1
  for (int c0 = 0; c0 < DOUT; c0 += 8) {
    float acc[8];
#pragma unroll
    for (int j = 0; j < 8; j++) acc[j] = FOLD ? browS[c0 + j] : 0.0f;
#pragma unroll
    for (int k = 0; k < 64; k++) {
      float xk = xs[k];
#pragma unroll
      for (int j = 0; j < 8; j++) acc[j] = fmaf(xk, W[k * DOUT + c0 + j], acc[j]);
    }
    uint4 st;
    st.x = (unsigned int)f2bf(di * acc[0]) | ((unsigned int)f2bf(di * acc[1]) << 16);
    st.y = (unsigned int)f2bf(di * acc[2]) | ((unsigned int)f2bf(di * acc[3]) << 16);
    st.z = (unsigned int)f2bf(di * acc[4]) | ((unsigned int)f2bf(di * acc[5]) << 16);
    st.w = (unsigned int)f2bf(di * acc[6]) | ((unsigned int)f2bf(di * acc[7]) << 16);
    *(uint4*)(Hs + (size_t)row * DOUT + c0) = st;
  }
}

// ---------------- gather aggregation, one wave per dst node ----------------
// dwordx2 quad-edge scheme: lane = eg*16+f4; lane owns features 4f4..4f4+3
// (uint2 = 2 dwords); the 4 edge-subgroups eg process 4 edges per shfl+load.
// Per edge: ~2.2 VALU + 0.25 bpermute + 0.25 load-inst. One wave per node
// (R8: many short waves beat few long ones); all __shfl full-exec (R6).
template <int DOUT, bool LSM>
__global__ __launch_bounds__(256) void k_agg(const unsigned int* __restrict__ Hs32,
                                             const int2* __restrict__ rowseg,
                                             const int* __restrict__ edges,
                                             const float* __restrict__ dinv,
                                             const float* __restrict__ bias,
                                             unsigned int* __restrict__ Ab32,
                                             float* __restrict__ emb,
                                             float* __restrict__ out,
                                             float* __restrict__ stats, int N) {
  constexpr int RD = DOUT / 2;      // dwords per row (32 or 20)
  constexpr int F4 = (RD + 1) / 2;  // active f4 lanes (16 or 10)
  int wid = (blockIdx.x * 256 + threadIdx.x) >> 6;
  int lane = threadIdx.x & 63;
  int wslot = threadIdx.x >> 6;
  int f4 = lane & 15;
  int eg = lane >> 4;  // edge subgroup 0..3
  bool fok = f4 < F4;
  int node = __builtin_amdgcn_readfirstlane(wid);
  bool active = node < N;
  float aL0 = 0.f, aH0 = 0.f, aL1 = 0.f, aH1 = 0.f;
  if (active) {
    int2 sg = rowseg[node];
    int beg = sg.x, end = sg.y;
    if (eg == 0 && fok) {  // self-loop term
      uint2 u = *(const uint2*)(Hs32 + (unsigned)node * RD + 2 * f4);
      aL0 = bf_lo(u.x); aH0 = bf_hi(u.x);
      aL1 = bf_lo(u.y); aH1 = bf_hi(u.y);
    }
    for (int b2 = beg; b2 < end; b2 += 64) {
      int cnt = min(64, end - b2);
      int srcv = edges[b2 + (lane < cnt ? lane : 0)];  // full-exec batch load
      int full = cnt & ~3;
      int j = 0;
      for (; j + 16 <= full; j += 16) {  // 4 loads in flight
        int s0 = __shfl(srcv, j + eg);
        int s1 = __shfl(srcv, j + 4 + eg);
        int s2 = __shfl(srcv, j + 8 + eg);
        int s3 = __shfl(srcv, j + 12 + eg);
        if (fok) {
          uint2 u0 = *(const uint2*)(Hs32 + (unsigned)(s0 * RD) + 2 * f4);
          uint2 u1 = *(const uint2*)(Hs32 + (unsigned)(s1 * RD) + 2 * f4);
          uint2 u2 = *(const uint2*)(Hs32 + (unsigned)(s2 * RD) + 2 * f4);
          uint2 u3 = *(const uint2*)(Hs32 + (unsigned)(s3 * RD) + 2 * f4);
          aL0 += bf_lo(u0.x); aH0 += bf_hi(u0.x); aL1 += bf_lo(u0.y); aH1 += bf_hi(u0.y);
          aL0 += bf_lo(u1.x); aH0 += bf_hi(u1.x); aL1 += bf_lo(u1.y); aH1 += bf_hi(u1.y);
          aL0 += bf_lo(u2.x); aH0 += bf_hi(u2.x); aL1 += bf_lo(u2.y); aH1 += bf_hi(u2.y);
          aL0 += bf_lo(u3.x); aH0 += bf_hi(u3.x); aL1 += bf_lo(u3.y); aH1 += bf_hi(u3.y);
        }
      }
      for (; j < full; j += 4) {
        int s0 = __shfl(srcv, j + eg);
        if (fok) {
          uint2 u0 = *(const uint2*)(Hs32 + (unsigned)(s0 * RD) + 2 * f4);
          aL0 += bf_lo(u0.x); aH0 += bf_hi(u0.x); aL1 += bf_lo(u0.y); aH1 += bf_hi(u0.y);
        }
      }
      int rem = cnt - full;  // 0..3
      if (rem) {
        int s0 = __shfl(srcv, full + (eg < rem ? eg : 0));  // full exec
        if (eg < rem && fok) {
          uint2 u0 = *(const uint2*)(Hs32 + (unsigned)(s0 * RD) + 2 * f4);
          aL0 += bf_lo(u0.x); aH0 += bf_hi(u0.x); aL1 += bf_lo(u0.y); aH1 += bf_hi(u0.y);
        }
      }
    }
    // reduce across the 4 edge subgroups: after xor16+xor32 every eg holds totals
    aL0 += __shfl_xor(aL0, 16); aH0 += __shfl_xor(aH0, 16);
    aL1 += __shfl_xor(aL1, 16); aH1 += __shfl_xor(aH1, 16);
    aL0 += __shfl_xor(aL0, 32); aH0 += __shfl_xor(aH0, 32);
    aL1 += __shfl_xor(aL1, 32); aH1 += __shfl_xor(aH1, 32);
    float dn = dinv[node];
    aL0 *= dn; aH0 *= dn; aL1 *= dn; aH1 *= dn;
  }
  if constexpr (!LSM) {
    if (active && eg == 0 && fok) {  // 16 lanes x 8B = full row, coalesced
      uint2 st;
      st.x = (unsigned int)f2bf(aL0) | ((unsigned int)f2bf(aH0) << 16);
      st.y = (unsigned int)f2bf(aL1) | ((unsigned int)f2bf(aH1) << 16);
      *(uint2*)(Ab32 + (unsigned)node * RD + 2 * f4) = st;
    }
    __shared__ float ls[4][64], ls2[4][64];
    if (eg == 0) {
      float v0 = (active && fok) ? aL0 : 0.f;
      float v1 = (active && fok) ? aH0 : 0.f;
      float v2 = (active && fok) ? aL1 : 0.f;
      float v3 = (active && fok) ? aH1 : 0.f;
      int base = 4 * f4;
      ls[wslot][base + 0] = v0; ls[wslot][base + 1] = v1;
      ls[wslot][base + 2] = v2; ls[wslot][base + 3] = v3;
      ls2[wslot][base + 0] = v0 * v0; ls2[wslot][base + 1] = v1 * v1;
      ls2[wslot][base + 2] = v2 * v2; ls2[wslot][base + 3] = v3 * v3;
    }
    __syncthreads();
    if (threadIdx.x < 64) {
      int t = threadIdx.x;
      float s = ls[0][t] + ls[1][t] + ls[2][t] + ls[3][t];
      float s2 = ls2[0][t] + ls2[1][t] + ls2[2][t] + ls2[3][t];
      int slot = blockIdx.x & (SLOTS - 1);
      atomicAdd(&stats[(size_t)slot * 128 + t], s);
      atomicAdd(&stats[(size_t)slot * 128 + 64 + t], s2);
    }
  } else {
    if (!active) return;  // wave-uniform
    if (fok) {
      const float4 bb = *(const float4*)(bias + 4 * f4);
      aL0 += bb.x; aH0 += bb.y; aL1 += bb.z; aH1 += bb.w;
    }
    float mx = fok ? fmaxf(fmaxf(aL0, aH0), fmaxf(aL1, aH1)) : -INFINITY;
#pragma unroll
    for (int off = 1; off < 16; off <<= 1) mx = fmaxf(mx, __shfl_xor(mx, off));
    float ex = fok ? (expf(aL0 - mx) + expf(aH0 - mx) + expf(aL1 - mx) +
                      expf(aH1 - mx))
                   : 0.0f;
#pragma unroll
    for (int off = 1; off < 16; off <<= 1) ex += __shfl_xor(ex, off);
    float lse = mx + logf(ex);
    if (eg == 0 && fok) {
      *(float4*)(emb + (size_t)node * DOUT + 4 * f4) =
          make_float4(aL0, aH0, aL1, aH1);
      *(float4*)(out + (size_t)node * DOUT + 4 * f4) =
          make_float4(aL0 - lse, aH0 - lse, aL1 - lse, aH1 - lse);
    }
  }
}

extern "C" void kernel_launch(void* const* d_in, const int* in_sizes, int n_in,
                              void* d_out, int out_size, void* d_ws, size_t ws_size,
                              hipStream_t stream) {
  const float* x = (const float*)d_in[0];
  const int* ei = (const int*)d_in[1];
  const float* W1 = (const float*)d_in[2];
  // b1 = d_in[3], b2 = d_in[5]: cancel exactly inside BatchNorm (mean subtraction)
  const float* W2 = (const float*)d_in[4];
  const float* W3 = (const float*)d_in[6];
  const float* b3 = (const float*)d_in[7];
  const float* g1 = (const float*)d_in[8];
  const float* be1 = (const float*)d_in[9];
  const float* g2 = (const float*)d_in[10];
  const float* be2 = (const float*)d_in[11];

  int N = in_sizes[0] / 64;
  int E = in_sizes[1] / 2;
  const int* src = ei;
  const int* dst = ei + E;
  int NB = (N + 127) / 128;  // 128-node buckets
  float invN = 1.0f / (float)N;

  char* ws = (char*)d_ws;
  int* gcount = (int*)ws;                           // [NBMAX]   (zeroed)
  float* stats1 = (float*)(gcount + NBMAX);         // [SLOTS*128] (zeroed by gemm1)
  float* stats2 = stats1 + SLOTS * 128;             // [SLOTS*128] (zeroed by gemm2)
  float* dinv = stats2 + SLOTS * 128;               // [N]
  int2* rowseg = (int2*)(dinv + N);                 // [N] (beg,end)
  unsigned short* Hs =
      (unsigned short*)(((uintptr_t)(rowseg + N) + 15) & ~(uintptr_t)15);  // [N*64] bf16
  unsigned short* Ab = Hs + (size_t)N * 64;         // [N*64] bf16
  int* edges = (int*)(Ab + (size_t)N * 64);         // [NBMAX*BCAP] bucket-strided
  int* staging = (int*)Hs;  // [NBMAX*BCAP] aliases Hs/Ab (consumed before gemm1)

  float* out = (float*)d_out;
  float* emb = (float*)d_out + (size_t)N * 40;

  dim3 B(256);
  int gN = (N + 255) / 256;
  int gW = (N + 3) / 4;  // one wave per node, 4 waves per block

  // ---- CSR build (+rowseg+dinv) ----
  hipMemsetAsync(gcount, 0, NBMAX * sizeof(int), stream);
  k_binA<<<(E + 4095) / 4096, B, 0, stream>>>(src, dst, gcount, staging, E, NB);
  k_binB<<<NB, B, 0, stream>>>(staging, gcount, rowseg, dinv, edges, N);

  // ---- layer 1 (zeroes stats1) ----
  k_gemm<64, false, false><<<gN, B, 0, stream>>>(x, W1, nullptr, nullptr, nullptr,
                                                 dinv, Hs, stats1, N, invN);
  k_agg<64, false><<<gW, B, 0, stream>>>((const unsigned int*)Hs, rowseg, edges, dinv,
                                         nullptr, (unsigned int*)Ab, nullptr, nullptr,
                                         stats1, N);

  // ---- layer 2 (BN1 fold fused; zeroes stats2) ----
  k_gemm<64, true, true><<<gN, B, 0, stream>>>(Ab, W2, stats1, g1, be1, dinv, Hs,
                                               stats2, N, invN);
  k_agg<64, false><<<gW, B, 0, stream>>>((const unsigned int*)Hs, rowseg, edges, dinv,
                                         nullptr, (unsigned int*)Ab, nullptr, nullptr,
                                         stats2, N);

  // ---- layer 3 (BN2 fold fused): gemm -> agg(+b3) -> fused log_softmax ----
  k_gemm<40, true, true><<<gN, B, 0, stream>>>(Ab, W3, stats2, g2, be2, dinv, Hs,
                                               nullptr, N, invN);
  k_agg<40, true><<<gW, B, 0, stream>>>((const unsigned int*)Hs, rowseg, edges, dinv,
                                        b3, nullptr, emb, out, nullptr, N);
}